// Round 11
// baseline (338.414 us; speedup 1.0000x reference)
//
#include <hip/hip_runtime.h>

typedef _Float16 half_t;
typedef _Float16 half8 __attribute__((ext_vector_type(8)));
typedef float f32x4 __attribute__((ext_vector_type(4)));

#define D_EMBED   1024
#define D_CROSS   768
#define N_HEADS   8
#define D_HEAD    128
#define BATCH     8
#define SEQ_Q     4096
#define SEQ_KV    77
#define SKV_PAD   80
#define NKV       (N_HEADS*SKV_PAD)     /* 640 */
#define NKV_PAD   768                   /* Bt1 N-rows padded for BN=256 tiling */
#define M_Q       (BATCH*SEQ_Q)         /* 32768 */

// ---------------- workspace layout (bytes) ----------------
#define WS_S     ((size_t)0)                                   // S/P in place: [32768][640] fp16, 3-bit swz, stride 1280B
#define WS_WQC   (WS_S    + (size_t)M_Q*NKV*2)
#define WS_WOT   (WS_WQC  + (size_t)D_EMBED*D_EMBED*2)
#define WS_WKVT  (WS_WOT  + (size_t)D_EMBED*D_EMBED*2)
#define WS_YH    (WS_WKVT + (size_t)2*D_EMBED*D_CROSS*2)
#define WS_KV    (WS_YH   + (size_t)BATCH*SKV_PAD*D_CROSS*2)
#define WS_BKV   (WS_KV   + (size_t)BATCH*SKV_PAD*2*D_EMBED*2)
#define WS_BT1   (WS_BKV  + (size_t)2*D_EMBED*4)               // W1^T fp16 [8][768][1024] 3-bit swz
#define WS_BT2   (WS_BT1  + (size_t)BATCH*NKV_PAD*D_EMBED*2)   // W2^T fp16 [8][1024][640] 3-bit swz
#define WS_C1    (WS_BT2  + (size_t)BATCH*D_EMBED*NKV*2)       // c1 fp32 [8][640]

#define ATTN_SCALE 0.08838834764831845f

__device__ __forceinline__ void gload_lds16(const void* g, void* lds) {
  __builtin_amdgcn_global_load_lds(
      (const __attribute__((address_space(1))) unsigned int*)g,
      (__attribute__((address_space(3))) unsigned int*)lds, 16, 0, 0);
}
__device__ __forceinline__ void BAR() {
  __builtin_amdgcn_s_barrier();
  __builtin_amdgcn_sched_barrier(0);
}

// ---------------- prep kernels ----------------
__global__ void cast_f32_f16(const float* __restrict__ src, half_t* __restrict__ dst) {
  int i = blockIdx.x * 256 + threadIdx.x;
  f32x4 a = *(const f32x4*)(src + (size_t)i*8);
  f32x4 b = *(const f32x4*)(src + (size_t)i*8 + 4);
  half8 h;
#pragma unroll
  for (int j = 0; j < 4; ++j) { h[j] = (half_t)a[j]; h[j+4] = (half_t)b[j]; }
  *(half8*)(dst + (size_t)i*8) = h;
}

__global__ void transpose_f32f16(const float* __restrict__ src, half_t* __restrict__ dst,
                                 int K, int N) {
  __shared__ float tile[32][33];
  int n0 = blockIdx.x * 32, k0 = blockIdx.y * 32;
  int tx = threadIdx.x, ty = threadIdx.y;
#pragma unroll
  for (int j = 0; j < 4; ++j)
    tile[ty + j*8][tx] = src[(size_t)(k0 + ty + j*8)*N + n0 + tx];
  __syncthreads();
#pragma unroll
  for (int j = 0; j < 4; ++j)
    dst[(size_t)(n0 + ty + j*8)*K + k0 + tx] = (half_t)tile[tx][ty + j*8];
}

__global__ void convert_pad_y(const float* __restrict__ y, half_t* __restrict__ yh) {
  int idx = blockIdx.x * 256 + threadIdx.x;
  int r = idx / D_CROSS, col = idx - r*D_CROSS;
  int b = r / SKV_PAD, s = r - b*SKV_PAD;
  yh[idx] = (s < SEQ_KV) ? (half_t)y[(size_t)(b*SEQ_KV + s)*D_CROSS + col] : (half_t)0.f;
}

__global__ void concat_bias(const float* __restrict__ bk, const float* __restrict__ bv,
                            float* __restrict__ bkv) {
  int i = blockIdx.x * 256 + threadIdx.x;
  bkv[i] = (i < D_EMBED) ? bk[i] : bv[i - D_EMBED];
}

// ---------------- 128x128 GEMM — K/V projection (R7-verified) ----------------
__global__ __launch_bounds__(256, 3)
void gemm_kv(const half_t* __restrict__ A, const half_t* __restrict__ Bt,
             const float* __restrict__ bias, half_t* __restrict__ C,
             int M, int N, int K) {
  __shared__ half_t As[3][128*32];
  __shared__ half_t Bs[2][128*32];
  const int tid = threadIdx.x;
  const int l = tid & 63, w = tid >> 6;
  const int l4 = l & 15, lh = l >> 4;
  const int bn0 = blockIdx.x * 128, bm0 = blockIdx.y * 128;
  const int wr = w >> 1, wc = w & 1;
  const int rslot = lh << 4;
  f32x4 acc[4][4] = {};
  const int nk = K >> 5;
  const int srow = w*16 + (l >> 2);
  const int scol = (l & 3)*8;

  auto stageB = [&](int kt, int bb) {
    const half_t* g = Bt + (size_t)(bn0 + srow)*K + scol + kt*32;
    gload_lds16(g,                 (char*)Bs[bb] + w*1024);
    gload_lds16(g + (size_t)64*K,  (char*)Bs[bb] + 4096 + w*1024);
  };
  auto stageA = [&](int kt, int bb) {
    const half_t* g = A + (size_t)(bm0 + srow)*K + scol + kt*32;
    gload_lds16(g,                 (char*)As[bb] + w*1024);
    gload_lds16(g + (size_t)64*K,  (char*)As[bb] + 4096 + w*1024);
  };
  auto compute = [&](int ab, int bb) {
    half8 af[4], bf[4];
#pragma unroll
    for (int m = 0; m < 4; ++m)
      af[m] = *(const half8*)((const char*)As[ab] + (size_t)(wr*64 + m*16 + l4)*64 + rslot);
#pragma unroll
    for (int n = 0; n < 4; ++n)
      bf[n] = *(const half8*)((const char*)Bs[bb] + (size_t)(wc*64 + n*16 + l4)*64 + rslot);
#pragma unroll
    for (int m = 0; m < 4; ++m)
#pragma unroll
      for (int n = 0; n < 4; ++n)
        acc[m][n] = __builtin_amdgcn_mfma_f32_16x16x32_f16(af[m], bf[n], acc[m][n], 0, 0, 0);
  };

  stageA(0, 0); stageA(1, 1); stageB(0, 0);
  asm volatile("s_waitcnt vmcnt(0)" ::: "memory");
  BAR();
  int aCur = 0, aP2 = 2;
  for (int t = 0; t < nk; ++t) {
    if (t + 1 < nk) stageB(t + 1, (t + 1) & 1);
    if (t + 2 < nk) stageA(t + 2, aP2);
    compute(aCur, t & 1);
    if (t + 1 < nk) {
      if (t + 2 < nk) { asm volatile("s_waitcnt vmcnt(2)" ::: "memory"); }
      else            { asm volatile("s_waitcnt vmcnt(0)" ::: "memory"); }
      BAR();
    }
    aCur = (aCur == 2) ? 0 : aCur + 1;
    aP2  = (aP2  == 2) ? 0 : aP2  + 1;
  }

  const int cb = bn0 + wc*64, rb = bm0 + wr*64;
#pragma unroll
  for (int n = 0; n < 4; ++n) {
    const int col = cb + n*16 + l4;
    const float bvv = bias[col];
#pragma unroll
    for (int m = 0; m < 4; ++m)
#pragma unroll
      for (int j = 0; j < 4; ++j)
        C[(size_t)(rb + m*16 + lh*4 + j)*N + col] = (half_t)(acc[m][n][j] + bvv);
  }
}

// ---------------- builders ----------------
// Bt1[b][r= h*80+s][k], 3-bit swizzle (slot ^= r&7 within 128B K-groups), row stride 2048B
__global__ __launch_bounds__(256, 2)
void w1_build(const half_t* __restrict__ kvb, const half_t* __restrict__ Wqc,
              half_t* __restrict__ Bt1) {
  __shared__ half_t K_lds[80*136];
  const int blk = blockIdx.x;
  const int b = blk >> 3, h = blk & 7;
  const int tid = threadIdx.x;
  const int l = tid & 63, w = tid >> 6;
  const int l4 = l & 15, lh = l >> 4;
  for (int i = tid; i < 80*16; i += 256) {
    int s = i >> 4, d = (i & 15) << 3;
    *(half8*)(K_lds + s*136 + d) =
        *(const half8*)(kvb + (size_t)(b*SKV_PAD + s)*2048 + h*128 + d);
  }
  __syncthreads();
  for (int c = 0; c < 4; ++c) {
    f32x4 acc[5][4] = {};
#pragma unroll
    for (int kt = 0; kt < 4; ++kt) {
      half8 af[5], bf[4];
#pragma unroll
      for (int m = 0; m < 5; ++m)
        af[m] = *(const half8*)(K_lds + (size_t)(m*16 + l4)*136 + kt*32 + lh*8);
#pragma unroll
      for (int n = 0; n < 4; ++n)
        bf[n] = *(const half8*)(Wqc + (size_t)(w*256 + c*64 + n*16 + l4)*1024 + h*128 + kt*32 + lh*8);
#pragma unroll
      for (int m = 0; m < 5; ++m)
#pragma unroll
        for (int n = 0; n < 4; ++n)
          acc[m][n] = __builtin_amdgcn_mfma_f32_16x16x32_f16(af[m], bf[n], acc[m][n], 0, 0, 0);
    }
#pragma unroll
    for (int n = 0; n < 4; ++n) {
      const int colk = w*256 + c*64 + n*16 + l4;
#pragma unroll
      for (int m = 0; m < 5; ++m)
#pragma unroll
        for (int j = 0; j < 4; ++j) {
          const int r = h*SKV_PAD + m*16 + lh*4 + j;
          size_t byte = ((size_t)(b*NKV_PAD + r))*2048 + (size_t)(colk >> 6)*128
                        + ((size_t)(((colk >> 3) & 7) ^ (r & 7)) << 4) + ((colk & 7) << 1);
          *(half_t*)((char*)Bt1 + byte) = (half_t)(acc[m][n][j]*ATTN_SCALE);
        }
    }
  }
}

// zero Bt1 pad rows 640..767 per batch (swizzle-aware: 16B slots align)
__global__ void zero_bt1_pad(half_t* __restrict__ Bt1) {
  int idx = blockIdx.x * 256 + threadIdx.x;        // 131072 threads x 8 halves
  int flat = idx * 8;
  int b = flat >> 17;
  int rem = flat & 131071;
  int row = NKV + (rem >> 10);
  int col = rem & 1023;
  size_t byte = ((size_t)(b*NKV_PAD + row))*2048 + (size_t)(col >> 6)*128
                + ((size_t)(((col >> 3) & 7) ^ (row & 7)) << 4);
  half8 z = {};
  *(half8*)((char*)Bt1 + byte) = z;
}

// Bt2[b][n][c= h*80+s], 3-bit swizzle, row stride 1280B (unchanged, R10-verified)
__global__ __launch_bounds__(256, 2)
void w2_build(const half_t* __restrict__ kvb, const half_t* __restrict__ Wot,
              half_t* __restrict__ Bt2) {
  __shared__ half_t V_lds[80*136];
  const int blk = blockIdx.x;
  const int b = blk >> 3, h = blk & 7;
  const int tid = threadIdx.x;
  const int l = tid & 63, w = tid >> 6;
  const int l4 = l & 15, lh = l >> 4;
  for (int i = tid; i < 80*16; i += 256) {
    int s = i >> 4, d = (i & 15) << 3;
    *(half8*)(V_lds + s*136 + d) =
        *(const half8*)(kvb + (size_t)(b*SKV_PAD + s)*2048 + 1024 + h*128 + d);
  }
  __syncthreads();
  for (int c = 0; c < 4; ++c) {
    f32x4 acc[4][5] = {};
#pragma unroll
    for (int kt = 0; kt < 4; ++kt) {
      half8 af[4], bf[5];
#pragma unroll
      for (int m = 0; m < 4; ++m)
        af[m] = *(const half8*)(Wot + (size_t)(w*256 + c*64 + m*16 + l4)*1024 + h*128 + kt*32 + lh*8);
#pragma unroll
      for (int n = 0; n < 5; ++n)
        bf[n] = *(const half8*)(V_lds + (size_t)(n*16 + l4)*136 + kt*32 + lh*8);
#pragma unroll
      for (int m = 0; m < 4; ++m)
#pragma unroll
        for (int n = 0; n < 5; ++n)
          acc[m][n] = __builtin_amdgcn_mfma_f32_16x16x32_f16(af[m], bf[n], acc[m][n], 0, 0, 0);
    }
#pragma unroll
    for (int m = 0; m < 4; ++m) {
#pragma unroll
      for (int j = 0; j < 4; ++j) {
        const int nrow = w*256 + c*64 + m*16 + lh*4 + j;
        const size_t rowbase = ((size_t)(b*1024 + nrow))*1280;
#pragma unroll
        for (int n = 0; n < 5; ++n) {
          const int cc = h*80 + n*16 + l4;
          size_t byte = rowbase + (size_t)(cc >> 6)*128
                        + ((size_t)(((cc >> 3) & 7) ^ (nrow & 7)) << 4) + ((cc & 7) << 1);
          *(half_t*)((char*)Bt2 + byte) = (half_t)acc[m][n][j];
        }
      }
    }
  }
}

__global__ void c1_build(const half_t* __restrict__ kvb, const float* __restrict__ bq,
                         float* __restrict__ c1) {
  int idx = blockIdx.x * 256 + threadIdx.x;
  int b = idx / NKV, n = idx - b*NKV;
  int h = n / SKV_PAD, s = n - h*SKV_PAD;
  const half_t* kp = kvb + (size_t)(b*SKV_PAD + s)*2048 + h*128;
  float acc = 0.f;
#pragma unroll 8
  for (int d = 0; d < 128; ++d) acc += bq[h*128 + d] * (float)kp[d];
  c1[idx] = acc * ATTN_SCALE;
}

// ---------------- shared 8-phase macro (R10-verified) ----------------
#define PH8(Q, ABASE, PRE, TAIL)                                                                     \
  {                                                                                                  \
    half8 a00 = *(const half8*)((ABASE) + (size_t)(arow0 + (2*(Q)  )*16)*128 + ak0);                 \
    half8 a01 = *(const half8*)((ABASE) + (size_t)(arow0 + (2*(Q)  )*16)*128 + ak1);                 \
    half8 a10 = *(const half8*)((ABASE) + (size_t)(arow0 + (2*(Q)+1)*16)*128 + ak0);                 \
    half8 a11 = *(const half8*)((ABASE) + (size_t)(arow0 + (2*(Q)+1)*16)*128 + ak1);                 \
    PRE;                                                                                             \
    __builtin_amdgcn_s_barrier();                                                                    \
    asm volatile("s_waitcnt lgkmcnt(0)" ::: "memory");                                               \
    __builtin_amdgcn_sched_barrier(0);                                                               \
    __builtin_amdgcn_s_setprio(1);                                                                   \
    _Pragma("unroll")                                                                                \
    for (int ni = 0; ni < 4; ++ni) {                                                                 \
      acc[2*(Q)  ][ni] = __builtin_amdgcn_mfma_f32_16x16x32_f16(a00, bf[ni][0], acc[2*(Q)  ][ni],0,0,0); \
      acc[2*(Q)  ][ni] = __builtin_amdgcn_mfma_f32_16x16x32_f16(a01, bf[ni][1], acc[2*(Q)  ][ni],0,0,0); \
      acc[2*(Q)+1][ni] = __builtin_amdgcn_mfma_f32_16x16x32_f16(a10, bf[ni][0], acc[2*(Q)+1][ni],0,0,0); \
      acc[2*(Q)+1][ni] = __builtin_amdgcn_mfma_f32_16x16x32_f16(a11, bf[ni][1], acc[2*(Q)+1][ni],0,0,0); \
    }                                                                                                \
    __builtin_amdgcn_s_setprio(0);                                                                   \
    TAIL;                                                                                            \
    __builtin_amdgcn_s_barrier();                                                                    \
    __builtin_amdgcn_sched_barrier(0);                                                               \
  }

// ---------------- S-GEMM: 256x256 8-phase, fp32-A reg-staged (T14-in-8-phase) ----------------
// S[32768,640] = x @ Bt1_b^T + c1_b. BN=256 over 640 (bx=2 half-pad). K=1024 -> 8 u-iters.
// A: aload (8xf32x4) in PH0, awrite (cvt + 4 swizzled ds_write_b128) in PH2 — its
// register dependence makes the compiler emit the counted vmcnt that also forces the
// previous B-prefetch landed. B: gload_lds from 3-bit-swizzled Bt1. Hand vmcnt only in prologue.
__global__ __launch_bounds__(512, 1)
void gemm8p_s(const float* __restrict__ X, const half_t* __restrict__ Bt1,
              const float* __restrict__ c1, half_t* __restrict__ S) {
  __shared__ half_t AbS[2*256*64];
  __shared__ half_t BbS[2*256*64];
  char* ABp = (char*)AbS;
  char* BBp = (char*)BbS;
  const int tid = threadIdx.x;
  const int l = tid & 63, w = tid >> 6;
  const int l4 = l & 15, lh = l >> 4;
  // 384 blocks = 8 XCDs x 48 (one batch each: 3 bx x 16 by)
  const int lin = ((int)blockIdx.x & 7)*48 + ((int)blockIdx.x >> 3);
  const int bx = lin % 3, by = lin / 3;
  const int bm0 = by << 8, bn0 = bx << 8;
  const int batch = by >> 4;
  const half_t* Bt = Bt1 + (size_t)batch*NKV_PAD*1024;
  const float* c1b = c1 + (size_t)batch*NKV;
  const int wr = w >> 2, wc = w & 3;
  const int ak0 = ((lh    ) ^ (l4 & 7)) << 4;
  const int ak1 = ((lh + 4) ^ (l4 & 7)) << 4;
  const int arow0 = wr*128 + l4;
  const int brow0 = wc*64 + l4;
  f32x4 acc[8][4] = {};
  half8 bf[4][2];

  // A reg staging: thread -> row tid>>1 (0..255), 32 floats at col (tid&1)*32
  f32x4 L[8];
  const int arow = tid >> 1;
  const int acb  = (tid & 1) * 32;
  const int akey = arow & 7;
  auto aload = [&](int kt) {
    const float* g = X + (size_t)(bm0 + arow)*1024 + kt*64 + acb;
#pragma unroll
    for (int j = 0; j < 8; ++j) L[j] = *(const f32x4*)(g + j*4);
  };
  auto awrite = [&](int db) {
    char* base = ABp + db*32768 + (size_t)arow*128;
#pragma unroll
    for (int j = 0; j < 4; ++j) {
      half8 h;
#pragma unroll
      for (int e = 0; e < 4; ++e) { h[e] = (half_t)L[2*j][e]; h[e+4] = (half_t)L[2*j+1][e]; }
      *(half8*)(base + ((((tid & 1)*4 + j) ^ akey) << 4)) = h;
    }
  };
  auto stB = [&](int kt, int db, int hf) {
#pragma unroll
    for (int r = 0; r < 2; ++r) {
      const int id = tid + r*512;
      gload_lds16((const char*)Bt + (size_t)(bn0 + hf*128 + (id >> 3))*2048 + (size_t)kt*128 + (id & 7)*16,
                  BBp + db*32768 + hf*16384 + r*8192 + w*1024);
    }
  };
  auto rdB = [&](const char* base) {
#pragma unroll
    for (int ni = 0; ni < 4; ++ni) {
      bf[ni][0] = *(const half8*)(base + (size_t)(brow0 + ni*16)*128 + ak0);
      bf[ni][1] = *(const half8*)(base + (size_t)(brow0 + ni*16)*128 + ak1);
    }
  };

  // prologue: A(0)->Abuf0 (reg->LDS), B(0)->buf0, B(1)->buf1; drain B0, keep B1 flying
  aload(0); awrite(0);
  stB(0, 0, 0); stB(0, 0, 1); stB(1, 1, 0); stB(1, 1, 1);
  asm volatile("s_waitcnt vmcnt(4) lgkmcnt(0)" ::: "memory");
  __builtin_amdgcn_sched_barrier(0);
  __builtin_amdgcn_s_barrier();

  const char* A0 = ABp;            const char* A1 = ABp + 32768;
  const char* B0 = BBp;            const char* B1 = BBp + 32768;

  for (int u = 0; u < 8; ++u) {
    const int kt0 = 2*u, kt1 = 2*u + 1;
    const bool nx = (u < 7);
    // ---- K-tile kt0 (bufs 0) ----
    PH8(0, A0, { rdB(B0); aload(kt1); }, {});
    PH8(1, A0, { if (nx) stB(kt0 + 2, 0, 0); }, {});
    PH8(2, A0, { if (nx) stB(kt0 + 2, 0, 1); awrite(1); }, {});
    PH8(3, A0, {}, {});
    // ---- K-tile kt1 (bufs 1) ----
    PH8(0, A1, { rdB(B1); if (nx) aload(kt0 + 2); }, {});
    PH8(1, A1, { if (nx) stB(kt1 + 2, 1, 0); }, {});
    PH8(2, A1, { if (nx) { stB(kt1 + 2, 1, 1); awrite(0); } }, {});
    PH8(3, A1, {}, {
      if (!nx) { asm volatile("s_waitcnt vmcnt(0)" ::: "memory"); }
    });
  }

  // epilogue: store S fp16, 3-bit swizzled, stride 1280B; skip pad cols (wave-uniform)
#pragma unroll
  for (int ni = 0; ni < 4; ++ni) {
    const int col = bn0 + wc*64 + ni*16 + l4;
    if (col < NKV) {
      const float bvv = c1b[col];
#pragma unroll
      for (int mi = 0; mi < 8; ++mi)
#pragma unroll
        for (int j = 0; j < 4; ++j) {
          const int row = bm0 + wr*128 + mi*16 + lh*4 + j;
          const float v = acc[mi][ni][j] + bvv;
          size_t byte = (size_t)row*1280 + (size_t)(col >> 6)*128
                        + ((size_t)(((col >> 3) & 7) ^ (row & 7)) << 4) + ((col & 7) << 1);
          *(half_t*)((char*)S + byte) = (half_t)v;
        }
    }
  }
}

// ---------------- softmax in place over swizzled S (R10-verified) ----------------
__global__ __launch_bounds__(256, 4)
void softmax_inplace(half_t* __restrict__ S) {
  const int gid = blockIdx.x * 256 + threadIdx.x;
  const int row = gid >> 3, h = gid & 7;
  const int key = row & 7;
  char* base = (char*)S + (size_t)row*1280;
  size_t off[10];
  half8 v[10];
#pragma unroll
  for (int i = 0; i < 10; ++i) {
    const int ls = h*10 + i;
    off[i] = (size_t)(ls >> 3)*128 + ((size_t)((ls & 7) ^ key) << 4);
    v[i] = *(const half8*)(base + off[i]);
  }
  float mx = -1e30f;
#pragma unroll
  for (int i = 0; i < 10; ++i)
#pragma unroll
    for (int j = 0; j < 8; ++j)
      if (i*8 + j < SEQ_KV) mx = fmaxf(mx, (float)v[i][j]);
  float sm = 0.f;
#pragma unroll
  for (int i = 0; i < 10; ++i) {
    half8 t = v[i];
#pragma unroll
    for (int j = 0; j < 8; ++j) {
      float e = (i*8 + j < SEQ_KV) ? __expf((float)t[j] - mx) : 0.f;
      sm += e; t[j] = (half_t)e;
    }
    v[i] = t;
  }
  const float inv = 1.f / sm;
#pragma unroll
  for (int i = 0; i < 10; ++i) {
    half8 t = v[i];
#pragma unroll
    for (int j = 0; j < 8; ++j) t[j] = (half_t)((float)t[j] * inv);
    *(half8*)(base + off[i]) = t;
  }
}

// ---------------- out-GEMM: 256x256 8-phase (R10-verified, unchanged) ----------------
__global__ __launch_bounds__(512, 1)
void gemm8p_out(const half_t* __restrict__ Sa, const half_t* __restrict__ Bt2,
                const float* __restrict__ bo, float* __restrict__ out) {
  __shared__ half_t AbS[2*256*64];
  __shared__ half_t BbS[2*256*64];
  char* ABp = (char*)AbS;
  char* BBp = (char*)BbS;
  const int tid = threadIdx.x;
  const int l = tid & 63, w = tid >> 6;
  const int l4 = l & 15, lh = l >> 4;
  const int lin = ((int)blockIdx.x & 7)*64 + ((int)blockIdx.x >> 3);
  const int bx = lin & 3, by = lin >> 2;
  const int bm0 = by << 8, bn0 = bx << 8;
  const half_t* Bt = Bt2 + (size_t)(by >> 4)*1024*640;
  const int wr = w >> 2, wc = w & 3;
  const int ak0 = ((lh    ) ^ (l4 & 7)) << 4;
  const int ak1 = ((lh + 4) ^ (l4 & 7)) << 4;
  const int arow0 = wr*128 + l4;
  const int brow0 = wc*64 + l4;
  f32x4 acc[8][4] = {};
  half8 bf[4][2];

  auto stA = [&](int kt, int db, int hf) {
#pragma unroll
    for (int r = 0; r < 2; ++r) {
      const int id = tid + r*512;
      gload_lds16((const char*)Sa + (size_t)(bm0 + hf*128 + (id >> 3))*1280 + (size_t)kt*128 + (id & 7)*16,
                  ABp + db*32768 + hf*16384 + r*8192 + w*1024);
    }
  };
  auto stB = [&](int kt, int db, int hf) {
#pragma unroll
    for (int r = 0; r < 2; ++r) {
      const int id = tid + r*512;
      gload_lds16((const char*)Bt + (size_t)(bn0 + hf*128 + (id >> 3))*1280 + (size_t)kt*128 + (id & 7)*16,
                  BBp + db*32768 + hf*16384 + r*8192 + w*1024);
    }
  };
  auto rdB = [&](const char* base) {
#pragma unroll
    for (int ni = 0; ni < 4; ++ni) {
      bf[ni][0] = *(const half8*)(base + (size_t)(brow0 + ni*16)*128 + ak0);
      bf[ni][1] = *(const half8*)(base + (size_t)(brow0 + ni*16)*128 + ak1);
    }
  };

  stA(0, 0, 0); stA(0, 0, 1); stB(0, 0, 0); stB(0, 0, 1); stB(1, 1, 0); stB(1, 1, 1);
  asm volatile("s_waitcnt vmcnt(4)" ::: "memory");
  __builtin_amdgcn_sched_barrier(0);
  __builtin_amdgcn_s_barrier();

  const char* A0 = ABp;            const char* A1 = ABp + 32768;
  const char* B0 = BBp;            const char* B1 = BBp + 32768;

  for (int u = 0; u < 5; ++u) {
    const int kt0 = 2*u, kt1 = 2*u + 1;
    const bool nx = (u < 4);
    PH8(0, A0, { rdB(B0); stA(kt1, 1, 0); stA(kt1, 1, 1); }, {});
    PH8(1, A0, { if (nx) stB(kt0 + 2, 0, 0); }, {});
    PH8(2, A0, { if (nx) stB(kt0 + 2, 0, 1); }, {});
    PH8(3, A0, {}, {
      if (nx) { asm volatile("s_waitcnt vmcnt(4)" ::: "memory"); }
      else    { asm volatile("s_waitcnt vmcnt(0)" ::: "memory"); }
      __builtin_amdgcn_sched_barrier(0);
    });
    PH8(0, A1, { rdB(B1); if (nx) stA(kt0 + 2, 0, 0); }, {});
    PH8(1, A1, { if (nx) stA(kt0 + 2, 0, 1); }, {});
    PH8(2, A1, { if (nx) stB(kt1 + 2, 1, 0); }, {});
    PH8(3, A1, { if (nx) stB(kt1 + 2, 1, 1); }, {
      if (nx) {
        asm volatile("s_waitcnt vmcnt(4)" ::: "memory");
        __builtin_amdgcn_sched_barrier(0);
      }
    });
  }

#pragma unroll
  for (int ni = 0; ni < 4; ++ni) {
    const int col = bn0 + wc*64 + ni*16 + l4;
    const float bvv = bo[col];
#pragma unroll
    for (int mi = 0; mi < 8; ++mi)
#pragma unroll
      for (int j = 0; j < 4; ++j) {
        const int row = bm0 + wr*128 + mi*16 + lh*4 + j;
        out[(size_t)row*1024 + col] = acc[mi][ni][j] + bvv;
      }
  }
}

// ---------------- launch ----------------
extern "C" void kernel_launch(void* const* d_in, const int* in_sizes, int n_in,
                              void* d_out, int out_size, void* d_ws, size_t ws_size,
                              hipStream_t stream) {
  (void)in_sizes; (void)n_in; (void)out_size; (void)ws_size;
  const float* x  = (const float*)d_in[0];
  const float* y  = (const float*)d_in[1];
  const float* Wq = (const float*)d_in[2];
  const float* bq = (const float*)d_in[3];
  const float* Wk = (const float*)d_in[4];
  const float* bk = (const float*)d_in[5];
  const float* Wv = (const float*)d_in[6];
  const float* bv = (const float*)d_in[7];
  const float* Wo = (const float*)d_in[8];
  const float* bo = (const float*)d_in[9];

  char* ws = (char*)d_ws;
  half_t* S    = (half_t*)(ws + WS_S);
  half_t* Wqc  = (half_t*)(ws + WS_WQC);
  half_t* Wot  = (half_t*)(ws + WS_WOT);
  half_t* Wkvt = (half_t*)(ws + WS_WKVT);
  half_t* yh   = (half_t*)(ws + WS_YH);
  half_t* kvb  = (half_t*)(ws + WS_KV);
  float*  bkv  = (float*)(ws + WS_BKV);
  half_t* Bt1  = (half_t*)(ws + WS_BT1);
  half_t* Bt2  = (half_t*)(ws + WS_BT2);
  float*  c1   = (float*)(ws + WS_C1);

  dim3 tb(32, 8);
  cast_f32_f16<<<512, 256, 0, stream>>>(Wq, Wqc);
  transpose_f32f16<<<dim3(32, 32), tb, 0, stream>>>(Wo, Wot, 1024, 1024);
  transpose_f32f16<<<dim3(32, 24), tb, 0, stream>>>(Wk, Wkvt, 768, 1024);
  transpose_f32f16<<<dim3(32, 24), tb, 0, stream>>>(Wv, Wkvt + (size_t)1024*768, 768, 1024);
  convert_pad_y<<<BATCH*SKV_PAD*D_CROSS/256, 256, 0, stream>>>(y, yh);
  concat_bias<<<2*D_EMBED/256, 256, 0, stream>>>(bk, bv, bkv);

  gemm_kv<<<dim3(16, 5), 256, 0, stream>>>(yh, Wkvt, bkv, kvb, BATCH*SKV_PAD, 2048, 768);

  c1_build<<<BATCH*NKV/256, 256, 0, stream>>>(kvb, bq, c1);
  w1_build<<<BATCH*N_HEADS, 256, 0, stream>>>(kvb, Wqc, Bt1);
  zero_bt1_pad<<<512, 256, 0, stream>>>(Bt1);
  w2_build<<<BATCH*N_HEADS, 256, 0, stream>>>(kvb, Wot, Bt2);

  // S = x @ W1[b] + c1[b] : 8-phase 256^2, fp32-A reg-staged
  gemm8p_s<<<384, 512, 0, stream>>>(x, Bt1, c1, S);

  // P = softmax(S), in place (swizzle-aware)
  softmax_inplace<<<M_Q*N_HEADS/256, 256, 0, stream>>>(S);

  // out = P @ W2[b] + bo : 8-phase 256^2
  gemm8p_out<<<512, 512, 0, stream>>>(S, Bt2, bo, (float*)d_out);
}

// Round 12
// 259.569 us; speedup vs baseline: 1.3038x; 1.3038x over previous
//
#include <hip/hip_runtime.h>

typedef _Float16 half_t;
typedef _Float16 half8 __attribute__((ext_vector_type(8)));
typedef float f32x4 __attribute__((ext_vector_type(4)));

#define D_EMBED   1024
#define D_CROSS   768
#define N_HEADS   8
#define D_HEAD    128
#define BATCH     8
#define SEQ_Q     4096
#define SEQ_KV    77
#define SKV_PAD   80
#define NKV       (N_HEADS*SKV_PAD)     /* 640 */
#define NKV_PAD   768                   /* Bt1 row-dim padding (rows 640..767 never read) */
#define M_Q       (BATCH*SEQ_Q)         /* 32768 */

// ---------------- workspace layout (bytes) ----------------
#define WS_S     ((size_t)0)                                   // (unused this round)
#define WS_WQC   (WS_S    + (size_t)M_Q*NKV*2)
#define WS_WOT   (WS_WQC  + (size_t)D_EMBED*D_EMBED*2)
#define WS_WKVT  (WS_WOT  + (size_t)D_EMBED*D_EMBED*2)
#define WS_YH    (WS_WKVT + (size_t)2*D_EMBED*D_CROSS*2)
#define WS_KV    (WS_YH   + (size_t)BATCH*SKV_PAD*D_CROSS*2)
#define WS_BKV   (WS_KV   + (size_t)BATCH*SKV_PAD*2*D_EMBED*2)
#define WS_BT1   (WS_BKV  + (size_t)2*D_EMBED*4)               // W1^T fp16 [8][768][1024] 3-bit swz, 2048B rows
#define WS_BT2   (WS_BT1  + (size_t)BATCH*NKV_PAD*D_EMBED*2)   // W2^T fp16 [8][1024][640] 3-bit swz, 1280B rows
#define WS_C1    (WS_BT2  + (size_t)BATCH*D_EMBED*NKV*2)       // c1 fp32 [8][640]

#define ATTN_SCALE 0.08838834764831845f

__device__ __forceinline__ void gload_lds16(const void* g, void* lds) {
  __builtin_amdgcn_global_load_lds(
      (const __attribute__((address_space(1))) unsigned int*)g,
      (__attribute__((address_space(3))) unsigned int*)lds, 16, 0, 0);
}
__device__ __forceinline__ void BAR() {
  __builtin_amdgcn_s_barrier();
  __builtin_amdgcn_sched_barrier(0);
}

// ---------------- prep kernels ----------------
__global__ void cast_f32_f16(const float* __restrict__ src, half_t* __restrict__ dst) {
  int i = blockIdx.x * 256 + threadIdx.x;
  f32x4 a = *(const f32x4*)(src + (size_t)i*8);
  f32x4 b = *(const f32x4*)(src + (size_t)i*8 + 4);
  half8 h;
#pragma unroll
  for (int j = 0; j < 4; ++j) { h[j] = (half_t)a[j]; h[j+4] = (half_t)b[j]; }
  *(half8*)(dst + (size_t)i*8) = h;
}

__global__ void transpose_f32f16(const float* __restrict__ src, half_t* __restrict__ dst,
                                 int K, int N) {
  __shared__ float tile[32][33];
  int n0 = blockIdx.x * 32, k0 = blockIdx.y * 32;
  int tx = threadIdx.x, ty = threadIdx.y;
#pragma unroll
  for (int j = 0; j < 4; ++j)
    tile[ty + j*8][tx] = src[(size_t)(k0 + ty + j*8)*N + n0 + tx];
  __syncthreads();
#pragma unroll
  for (int j = 0; j < 4; ++j)
    dst[(size_t)(n0 + ty + j*8)*K + k0 + tx] = (half_t)tile[tx][ty + j*8];
}

__global__ void convert_pad_y(const float* __restrict__ y, half_t* __restrict__ yh) {
  int idx = blockIdx.x * 256 + threadIdx.x;
  int r = idx / D_CROSS, col = idx - r*D_CROSS;
  int b = r / SKV_PAD, s = r - b*SKV_PAD;
  yh[idx] = (s < SEQ_KV) ? (half_t)y[(size_t)(b*SEQ_KV + s)*D_CROSS + col] : (half_t)0.f;
}

__global__ void concat_bias(const float* __restrict__ bk, const float* __restrict__ bv,
                            float* __restrict__ bkv) {
  int i = blockIdx.x * 256 + threadIdx.x;
  bkv[i] = (i < D_EMBED) ? bk[i] : bv[i - D_EMBED];
}

// ---------------- 128x128 GEMM — K/V projection (R7-verified) ----------------
__global__ __launch_bounds__(256, 3)
void gemm_kv(const half_t* __restrict__ A, const half_t* __restrict__ Bt,
             const float* __restrict__ bias, half_t* __restrict__ C,
             int M, int N, int K) {
  __shared__ half_t As[3][128*32];
  __shared__ half_t Bs[2][128*32];
  const int tid = threadIdx.x;
  const int l = tid & 63, w = tid >> 6;
  const int l4 = l & 15, lh = l >> 4;
  const int bn0 = blockIdx.x * 128, bm0 = blockIdx.y * 128;
  const int wr = w >> 1, wc = w & 1;
  const int rslot = lh << 4;
  f32x4 acc[4][4] = {};
  const int nk = K >> 5;
  const int srow = w*16 + (l >> 2);
  const int scol = (l & 3)*8;

  auto stageB = [&](int kt, int bb) {
    const half_t* g = Bt + (size_t)(bn0 + srow)*K + scol + kt*32;
    gload_lds16(g,                 (char*)Bs[bb] + w*1024);
    gload_lds16(g + (size_t)64*K,  (char*)Bs[bb] + 4096 + w*1024);
  };
  auto stageA = [&](int kt, int bb) {
    const half_t* g = A + (size_t)(bm0 + srow)*K + scol + kt*32;
    gload_lds16(g,                 (char*)As[bb] + w*1024);
    gload_lds16(g + (size_t)64*K,  (char*)As[bb] + 4096 + w*1024);
  };
  auto compute = [&](int ab, int bb) {
    half8 af[4], bf[4];
#pragma unroll
    for (int m = 0; m < 4; ++m)
      af[m] = *(const half8*)((const char*)As[ab] + (size_t)(wr*64 + m*16 + l4)*64 + rslot);
#pragma unroll
    for (int n = 0; n < 4; ++n)
      bf[n] = *(const half8*)((const char*)Bs[bb] + (size_t)(wc*64 + n*16 + l4)*64 + rslot);
#pragma unroll
    for (int m = 0; m < 4; ++m)
#pragma unroll
      for (int n = 0; n < 4; ++n)
        acc[m][n] = __builtin_amdgcn_mfma_f32_16x16x32_f16(af[m], bf[n], acc[m][n], 0, 0, 0);
  };

  stageA(0, 0); stageA(1, 1); stageB(0, 0);
  asm volatile("s_waitcnt vmcnt(0)" ::: "memory");
  BAR();
  int aCur = 0, aP2 = 2;
  for (int t = 0; t < nk; ++t) {
    if (t + 1 < nk) stageB(t + 1, (t + 1) & 1);
    if (t + 2 < nk) stageA(t + 2, aP2);
    compute(aCur, t & 1);
    if (t + 1 < nk) {
      if (t + 2 < nk) { asm volatile("s_waitcnt vmcnt(2)" ::: "memory"); }
      else            { asm volatile("s_waitcnt vmcnt(0)" ::: "memory"); }
      BAR();
    }
    aCur = (aCur == 2) ? 0 : aCur + 1;
    aP2  = (aP2  == 2) ? 0 : aP2  + 1;
  }

  const int cb = bn0 + wc*64, rb = bm0 + wr*64;
#pragma unroll
  for (int n = 0; n < 4; ++n) {
    const int col = cb + n*16 + l4;
    const float bvv = bias[col];
#pragma unroll
    for (int m = 0; m < 4; ++m)
#pragma unroll
      for (int j = 0; j < 4; ++j)
        C[(size_t)(rb + m*16 + lh*4 + j)*N + col] = (half_t)(acc[m][n][j] + bvv);
  }
}

// ---------------- builders (R11-verified) ----------------
// Bt1[b][r=h*80+s][k], 2048B rows, 3-bit swizzle (slot ^= r&7 within 128B K-groups)
__global__ __launch_bounds__(256, 2)
void w1_build(const half_t* __restrict__ kvb, const half_t* __restrict__ Wqc,
              half_t* __restrict__ Bt1) {
  __shared__ half_t K_lds[80*136];
  const int blk = blockIdx.x;
  const int b = blk >> 3, h = blk & 7;
  const int tid = threadIdx.x;
  const int l = tid & 63, w = tid >> 6;
  const int l4 = l & 15, lh = l >> 4;
  for (int i = tid; i < 80*16; i += 256) {
    int s = i >> 4, d = (i & 15) << 3;
    *(half8*)(K_lds + s*136 + d) =
        *(const half8*)(kvb + (size_t)(b*SKV_PAD + s)*2048 + h*128 + d);
  }
  __syncthreads();
  for (int c = 0; c < 4; ++c) {
    f32x4 acc[5][4] = {};
#pragma unroll
    for (int kt = 0; kt < 4; ++kt) {
      half8 af[5], bf[4];
#pragma unroll
      for (int m = 0; m < 5; ++m)
        af[m] = *(const half8*)(K_lds + (size_t)(m*16 + l4)*136 + kt*32 + lh*8);
#pragma unroll
      for (int n = 0; n < 4; ++n)
        bf[n] = *(const half8*)(Wqc + (size_t)(w*256 + c*64 + n*16 + l4)*1024 + h*128 + kt*32 + lh*8);
#pragma unroll
      for (int m = 0; m < 5; ++m)
#pragma unroll
        for (int n = 0; n < 4; ++n)
          acc[m][n] = __builtin_amdgcn_mfma_f32_16x16x32_f16(af[m], bf[n], acc[m][n], 0, 0, 0);
    }
#pragma unroll
    for (int n = 0; n < 4; ++n) {
      const int colk = w*256 + c*64 + n*16 + l4;
#pragma unroll
      for (int m = 0; m < 5; ++m)
#pragma unroll
        for (int j = 0; j < 4; ++j) {
          const int r = h*SKV_PAD + m*16 + lh*4 + j;
          size_t byte = ((size_t)(b*NKV_PAD + r))*2048 + (size_t)(colk >> 6)*128
                        + ((size_t)(((colk >> 3) & 7) ^ (r & 7)) << 4) + ((colk & 7) << 1);
          *(half_t*)((char*)Bt1 + byte) = (half_t)(acc[m][n][j]*ATTN_SCALE);
        }
    }
  }
}

// Bt2[b][n][c=h*80+s], 1280B rows, 3-bit swizzle (R10-verified)
__global__ __launch_bounds__(256, 2)
void w2_build(const half_t* __restrict__ kvb, const half_t* __restrict__ Wot,
              half_t* __restrict__ Bt2) {
  __shared__ half_t V_lds[80*136];
  const int blk = blockIdx.x;
  const int b = blk >> 3, h = blk & 7;
  const int tid = threadIdx.x;
  const int l = tid & 63, w = tid >> 6;
  const int l4 = l & 15, lh = l >> 4;
  for (int i = tid; i < 80*16; i += 256) {
    int s = i >> 4, d = (i & 15) << 3;
    *(half8*)(V_lds + s*136 + d) =
        *(const half8*)(kvb + (size_t)(b*SKV_PAD + s)*2048 + 1024 + h*128 + d);
  }
  __syncthreads();
  for (int c = 0; c < 4; ++c) {
    f32x4 acc[4][5] = {};
#pragma unroll
    for (int kt = 0; kt < 4; ++kt) {
      half8 af[4], bf[5];
#pragma unroll
      for (int m = 0; m < 4; ++m)
        af[m] = *(const half8*)(Wot + (size_t)(w*256 + c*64 + m*16 + l4)*1024 + h*128 + kt*32 + lh*8);
#pragma unroll
      for (int n = 0; n < 5; ++n)
        bf[n] = *(const half8*)(V_lds + (size_t)(n*16 + l4)*136 + kt*32 + lh*8);
#pragma unroll
      for (int m = 0; m < 4; ++m)
#pragma unroll
        for (int n = 0; n < 5; ++n)
          acc[m][n] = __builtin_amdgcn_mfma_f32_16x16x32_f16(af[m], bf[n], acc[m][n], 0, 0, 0);
    }
#pragma unroll
    for (int m = 0; m < 4; ++m) {
#pragma unroll
      for (int j = 0; j < 4; ++j) {
        const int nrow = w*256 + c*64 + m*16 + lh*4 + j;
        const size_t rowbase = ((size_t)(b*1024 + nrow))*1280;
#pragma unroll
        for (int n = 0; n < 5; ++n) {
          const int cc = h*80 + n*16 + l4;
          size_t byte = rowbase + (size_t)(cc >> 6)*128
                        + ((size_t)(((cc >> 3) & 7) ^ (nrow & 7)) << 4) + ((cc & 7) << 1);
          *(half_t*)((char*)Bt2 + byte) = (half_t)acc[m][n][j];
        }
      }
    }
  }
}

__global__ void c1_build(const half_t* __restrict__ kvb, const float* __restrict__ bq,
                         float* __restrict__ c1) {
  int idx = blockIdx.x * 256 + threadIdx.x;
  int b = idx / NKV, n = idx - b*NKV;
  int h = n / SKV_PAD, s = n - h*SKV_PAD;
  const half_t* kp = kvb + (size_t)(b*SKV_PAD + s)*2048 + h*128;
  float acc = 0.f;
#pragma unroll 8
  for (int d = 0; d < 128; ++d) acc += bq[h*128 + d] * (float)kp[d];
  c1[idx] = acc * ATTN_SCALE;
}

// ---------------- FUSED: S = x@W1 -> softmax (LDS) -> out = P@W2 ----------------
// One block per 64-row tile. 512 thr / 8 waves. S never touches HBM.
// S_lds: [64 rows][640] fp16, 1280B rows, 3-bit swizzle (= verified global-S layout).
// x staged per BK=64 chunk (fp32->fp16 reg-split, R7's T14 pattern), 3-bit-swizzled 128B rows.
// W1/W2 B-frags read directly from L2 (per-XCD batch residency; no cross-wave redundancy).
__global__ __launch_bounds__(512, 2)
void fused_sv(const float* __restrict__ X, const half_t* __restrict__ Bt1,
              const float* __restrict__ c1, const half_t* __restrict__ Bt2,
              const float* __restrict__ bo, float* __restrict__ out) {
  __shared__ half_t S_lds[64*640];       // 80 KB
  __shared__ half_t x_lds[2][64*64];     // 2 x 8 KB
  const int tid = threadIdx.x;
  const int l = tid & 63, w = tid >> 6;
  const int l4 = l & 15, lh = l >> 4;
  const int k7 = l4 & 7;                 // per-lane swizzle key (row&7 == l4&7 on all frag paths)

  // XCD-chunked: blocks with equal blk&7 share an XCD; each XCD owns one batch.
  const int lin = ((int)blockIdx.x & 7)*64 + ((int)blockIdx.x >> 3);
  const int batch = lin >> 6;
  const int row0 = batch*SEQ_Q + (lin & 63)*64;
  const half_t* W1 = Bt1 + (size_t)batch*NKV_PAD*1024;   // 2048B rows (rows 0..639 used)
  const half_t* W2 = Bt2 + (size_t)batch*1024*NKV;       // 1280B rows
  const float* c1b = c1 + batch*NKV;

  // ================= S phase: S[64x640] = x[64x1024] @ W1^T =================
  // wave w owns n-frags [w*5, w*5+5) (cols w*80..w*80+80), all 4 m-frags.
  f32x4 sacc[4][5] = {};
  const int nfb = w*5;

  // x reg-staging: thread -> row tid>>3, 8 floats at col (tid&7)*8
  const int xrow = tid >> 3, xc8 = tid & 7;
  const float* xg = X + (size_t)(row0 + xrow)*1024 + xc8*8;
  f32x4 xa, xb;
  auto xload = [&](int kc) {
    const float* g = xg + kc*64;
    xa = *(const f32x4*)g; xb = *(const f32x4*)(g + 4);
  };
  auto xwrite = [&](int buf) {
    half8 h;
#pragma unroll
    for (int e = 0; e < 4; ++e) { h[e] = (half_t)xa[e]; h[e+4] = (half_t)xb[e]; }
    *(half8*)((char*)x_lds[buf] + xrow*128 + ((xc8 ^ (xrow & 7)) << 4)) = h;
  };

  xload(0); xwrite(0);
  __syncthreads();

  for (int kc = 0; kc < 16; ++kc) {
    if (kc + 1 < 16) xload(kc + 1);                    // issue early (T14)
    const char* xc = (const char*)x_lds[kc & 1];
#pragma unroll
    for (int kk = 0; kk < 2; ++kk) {
      half8 af[4];
#pragma unroll
      for (int m = 0; m < 4; ++m)
        af[m] = *(const half8*)(xc + (size_t)(m*16 + l4)*128 + (((kk*4 + lh) ^ k7) << 4));
#pragma unroll
      for (int nf = 0; nf < 5; ++nf) {
        const int nrow = (nfb + nf)*16 + l4;
        half8 bfv = *(const half8*)((const char*)W1 + (size_t)nrow*2048 + (size_t)kc*128
                                    + (((kk*4 + lh) ^ k7) << 4));
#pragma unroll
        for (int m = 0; m < 4; ++m)
          sacc[m][nf] = __builtin_amdgcn_mfma_f32_16x16x32_f16(af[m], bfv, sacc[m][nf], 0, 0, 0);
      }
    }
    if (kc + 1 < 16) {
      xwrite((kc + 1) & 1);                            // cvt + ds_write late
      __syncthreads();
    }
  }

  // dump S-frags to S_lds (3-bit swizzle; same math as verified gemm8p_s epilogue)
#pragma unroll
  for (int nf = 0; nf < 5; ++nf) {
    const int col = (nfb + nf)*16 + l4;
#pragma unroll
    for (int m = 0; m < 4; ++m)
#pragma unroll
      for (int j = 0; j < 4; ++j) {
        const int row = m*16 + lh*4 + j;
        size_t byte = (size_t)row*1280 + (size_t)(col >> 6)*128
                      + ((size_t)(((col >> 3) & 7) ^ (row & 7)) << 4) + ((col & 7) << 1);
        *(half_t*)((char*)S_lds + byte) = (half_t)sacc[m][nf][j];
      }
  }
  __syncthreads();

  // ================= softmax in LDS (thread = one (row, head)) =================
  {
    const int row = tid >> 3, h = tid & 7;
    const int key = row & 7;
    char* base = (char*)S_lds + (size_t)row*1280;
    float fv[10][8];
    float mx = -1e30f;
#pragma unroll
    for (int i = 0; i < 10; ++i) {
      const int ls = h*10 + i;
      half8 v = *(const half8*)(base + (size_t)(ls >> 3)*128 + ((size_t)((ls & 7) ^ key) << 4));
      f32x4 ca = *(const f32x4*)(c1b + h*80 + i*8);
      f32x4 cb = *(const f32x4*)(c1b + h*80 + i*8 + 4);
#pragma unroll
      for (int j = 0; j < 8; ++j) {
        const float cc = (j < 4) ? ca[j] : cb[j - 4];
        const float sv = (float)v[j] + cc;
        const bool ok = (i*8 + j) < SEQ_KV;
        fv[i][j] = ok ? sv : -1e30f;
        if (ok) mx = fmaxf(mx, sv);
      }
    }
    float sm = 0.f;
#pragma unroll
    for (int i = 0; i < 10; ++i)
#pragma unroll
      for (int j = 0; j < 8; ++j) { float e = __expf(fv[i][j] - mx); sm += e; fv[i][j] = e; }
    const float inv = 1.f / sm;
#pragma unroll
    for (int i = 0; i < 10; ++i) {
      const int ls = h*10 + i;
      half8 t;
#pragma unroll
      for (int j = 0; j < 8; ++j) t[j] = (half_t)(fv[i][j] * inv);
      *(half8*)(base + (size_t)(ls >> 3)*128 + ((size_t)((ls & 7) ^ key) << 4)) = t;
    }
  }
  __syncthreads();

  // ================= P phase: out[64x1024] = P[64x640] @ W2^T =================
  // wave w owns out cols [w*128, w*128+128): 4 m-frags x 8 n-frags.
  f32x4 oacc[4][8] = {};
  const int ncb = w*128;
  for (int ks = 0; ks < 20; ++ks) {
    const size_t koff = (size_t)(ks >> 1)*128 + ((((ks & 1)*4 + lh) ^ k7) << 4);
    half8 af[4];
#pragma unroll
    for (int m = 0; m < 4; ++m)
      af[m] = *(const half8*)((const char*)S_lds + (size_t)(m*16 + l4)*1280 + koff);
#pragma unroll
    for (int nf = 0; nf < 8; ++nf) {
      const int nrow = ncb + nf*16 + l4;
      half8 bfv = *(const half8*)((const char*)W2 + (size_t)nrow*1280 + koff);
#pragma unroll
      for (int m = 0; m < 4; ++m)
        oacc[m][nf] = __builtin_amdgcn_mfma_f32_16x16x32_f16(af[m], bfv, oacc[m][nf], 0, 0, 0);
    }
  }

  // epilogue: out fp32 + bo
#pragma unroll
  for (int nf = 0; nf < 8; ++nf) {
    const int col = ncb + nf*16 + l4;
    const float bvv = bo[col];
#pragma unroll
    for (int m = 0; m < 4; ++m)
#pragma unroll
      for (int j = 0; j < 4; ++j) {
        const int row = row0 + m*16 + lh*4 + j;
        out[(size_t)row*1024 + col] = oacc[m][nf][j] + bvv;
      }
  }
}

// ---------------- launch ----------------
extern "C" void kernel_launch(void* const* d_in, const int* in_sizes, int n_in,
                              void* d_out, int out_size, void* d_ws, size_t ws_size,
                              hipStream_t stream) {
  (void)in_sizes; (void)n_in; (void)out_size; (void)ws_size;
  const float* x  = (const float*)d_in[0];
  const float* y  = (const float*)d_in[1];
  const float* Wq = (const float*)d_in[2];
  const float* bq = (const float*)d_in[3];
  const float* Wk = (const float*)d_in[4];
  const float* bk = (const float*)d_in[5];
  const float* Wv = (const float*)d_in[6];
  const float* bv = (const float*)d_in[7];
  const float* Wo = (const float*)d_in[8];
  const float* bo = (const float*)d_in[9];

  char* ws = (char*)d_ws;
  half_t* Wqc  = (half_t*)(ws + WS_WQC);
  half_t* Wot  = (half_t*)(ws + WS_WOT);
  half_t* Wkvt = (half_t*)(ws + WS_WKVT);
  half_t* yh   = (half_t*)(ws + WS_YH);
  half_t* kvb  = (half_t*)(ws + WS_KV);
  float*  bkv  = (float*)(ws + WS_BKV);
  half_t* Bt1  = (half_t*)(ws + WS_BT1);
  half_t* Bt2  = (half_t*)(ws + WS_BT2);
  float*  c1   = (float*)(ws + WS_C1);

  dim3 tb(32, 8);
  cast_f32_f16<<<512, 256, 0, stream>>>(Wq, Wqc);
  transpose_f32f16<<<dim3(32, 32), tb, 0, stream>>>(Wo, Wot, 1024, 1024);
  transpose_f32f16<<<dim3(32, 24), tb, 0, stream>>>(Wk, Wkvt, 768, 1024);
  transpose_f32f16<<<dim3(32, 24), tb, 0, stream>>>(Wv, Wkvt + (size_t)1024*768, 768, 1024);
  convert_pad_y<<<BATCH*SKV_PAD*D_CROSS/256, 256, 0, stream>>>(y, yh);
  concat_bias<<<2*D_EMBED/256, 256, 0, stream>>>(bk, bv, bkv);

  // K/V projection
  gemm_kv<<<dim3(16, 5), 256, 0, stream>>>(yh, Wkvt, bkv, kvb, BATCH*SKV_PAD, 2048, 768);

  // folded-weight builders
  c1_build<<<BATCH*NKV/256, 256, 0, stream>>>(kvb, bq, c1);
  w1_build<<<BATCH*N_HEADS, 256, 0, stream>>>(kvb, Wqc, Bt1);
  w2_build<<<BATCH*N_HEADS, 256, 0, stream>>>(kvb, Wot, Bt2);

  // fused S-GEMM + softmax + out-GEMM (S stays in LDS)
  fused_sv<<<512, 512, 0, stream>>>(x, Bt1, c1, Bt2, bo, (float*)d_out);
}

// Round 13
// 258.954 us; speedup vs baseline: 1.3069x; 1.0024x over previous
//
#include <hip/hip_runtime.h>

typedef _Float16 half_t;
typedef _Float16 half8 __attribute__((ext_vector_type(8)));
typedef float f32x4 __attribute__((ext_vector_type(4)));

#define D_EMBED   1024
#define D_CROSS   768
#define N_HEADS   8
#define D_HEAD    128
#define BATCH     8
#define SEQ_Q     4096
#define SEQ_KV    77
#define SKV_PAD   80
#define NKV       (N_HEADS*SKV_PAD)     /* 640 */
#define NKV_PAD   768                   /* Bt1 row-dim padding (rows 640..767 never read) */
#define M_Q       (BATCH*SEQ_Q)         /* 32768 */

// ---------------- workspace layout (bytes) ----------------
#define WS_S     ((size_t)0)                                   // (unused this round)
#define WS_WQC   (WS_S    + (size_t)M_Q*NKV*2)
#define WS_WOT   (WS_WQC  + (size_t)D_EMBED*D_EMBED*2)
#define WS_WKVT  (WS_WOT  + (size_t)D_EMBED*D_EMBED*2)
#define WS_YH    (WS_WKVT + (size_t)2*D_EMBED*D_CROSS*2)
#define WS_KV    (WS_YH   + (size_t)BATCH*SKV_PAD*D_CROSS*2)
#define WS_BKV   (WS_KV   + (size_t)BATCH*SKV_PAD*2*D_EMBED*2)
#define WS_BT1   (WS_BKV  + (size_t)2*D_EMBED*4)               // W1^T fp16 [8][768][1024] 3-bit swz, 2048B rows
#define WS_BT2   (WS_BT1  + (size_t)BATCH*NKV_PAD*D_EMBED*2)   // W2^T fp16 [8][1024][640] 3-bit swz, 1280B rows
#define WS_C1    (WS_BT2  + (size_t)BATCH*D_EMBED*NKV*2)       // c1 fp32 [8][640]

#define ATTN_SCALE 0.08838834764831845f

__device__ __forceinline__ void gload_lds16(const void* g, void* lds) {
  __builtin_amdgcn_global_load_lds(
      (const __attribute__((address_space(1))) unsigned int*)g,
      (__attribute__((address_space(3))) unsigned int*)lds, 16, 0, 0);
}
__device__ __forceinline__ void BAR() {
  __builtin_amdgcn_s_barrier();
  __builtin_amdgcn_sched_barrier(0);
}

// ---------------- prep kernels ----------------
__global__ void cast_f32_f16(const float* __restrict__ src, half_t* __restrict__ dst) {
  int i = blockIdx.x * 256 + threadIdx.x;
  f32x4 a = *(const f32x4*)(src + (size_t)i*8);
  f32x4 b = *(const f32x4*)(src + (size_t)i*8 + 4);
  half8 h;
#pragma unroll
  for (int j = 0; j < 4; ++j) { h[j] = (half_t)a[j]; h[j+4] = (half_t)b[j]; }
  *(half8*)(dst + (size_t)i*8) = h;
}

__global__ void transpose_f32f16(const float* __restrict__ src, half_t* __restrict__ dst,
                                 int K, int N) {
  __shared__ float tile[32][33];
  int n0 = blockIdx.x * 32, k0 = blockIdx.y * 32;
  int tx = threadIdx.x, ty = threadIdx.y;
#pragma unroll
  for (int j = 0; j < 4; ++j)
    tile[ty + j*8][tx] = src[(size_t)(k0 + ty + j*8)*N + n0 + tx];
  __syncthreads();
#pragma unroll
  for (int j = 0; j < 4; ++j)
    dst[(size_t)(n0 + ty + j*8)*K + k0 + tx] = (half_t)tile[tx][ty + j*8];
}

__global__ void convert_pad_y(const float* __restrict__ y, half_t* __restrict__ yh) {
  int idx = blockIdx.x * 256 + threadIdx.x;
  int r = idx / D_CROSS, col = idx - r*D_CROSS;
  int b = r / SKV_PAD, s = r - b*SKV_PAD;
  yh[idx] = (s < SEQ_KV) ? (half_t)y[(size_t)(b*SEQ_KV + s)*D_CROSS + col] : (half_t)0.f;
}

__global__ void concat_bias(const float* __restrict__ bk, const float* __restrict__ bv,
                            float* __restrict__ bkv) {
  int i = blockIdx.x * 256 + threadIdx.x;
  bkv[i] = (i < D_EMBED) ? bk[i] : bv[i - D_EMBED];
}

// ---------------- 128x128 GEMM — K/V projection (R7-verified) ----------------
__global__ __launch_bounds__(256, 3)
void gemm_kv(const half_t* __restrict__ A, const half_t* __restrict__ Bt,
             const float* __restrict__ bias, half_t* __restrict__ C,
             int M, int N, int K) {
  __shared__ half_t As[3][128*32];
  __shared__ half_t Bs[2][128*32];
  const int tid = threadIdx.x;
  const int l = tid & 63, w = tid >> 6;
  const int l4 = l & 15, lh = l >> 4;
  const int bn0 = blockIdx.x * 128, bm0 = blockIdx.y * 128;
  const int wr = w >> 1, wc = w & 1;
  const int rslot = lh << 4;
  f32x4 acc[4][4] = {};
  const int nk = K >> 5;
  const int srow = w*16 + (l >> 2);
  const int scol = (l & 3)*8;

  auto stageB = [&](int kt, int bb) {
    const half_t* g = Bt + (size_t)(bn0 + srow)*K + scol + kt*32;
    gload_lds16(g,                 (char*)Bs[bb] + w*1024);
    gload_lds16(g + (size_t)64*K,  (char*)Bs[bb] + 4096 + w*1024);
  };
  auto stageA = [&](int kt, int bb) {
    const half_t* g = A + (size_t)(bm0 + srow)*K + scol + kt*32;
    gload_lds16(g,                 (char*)As[bb] + w*1024);
    gload_lds16(g + (size_t)64*K,  (char*)As[bb] + 4096 + w*1024);
  };
  auto compute = [&](int ab, int bb) {
    half8 af[4], bf[4];
#pragma unroll
    for (int m = 0; m < 4; ++m)
      af[m] = *(const half8*)((const char*)As[ab] + (size_t)(wr*64 + m*16 + l4)*64 + rslot);
#pragma unroll
    for (int n = 0; n < 4; ++n)
      bf[n] = *(const half8*)((const char*)Bs[bb] + (size_t)(wc*64 + n*16 + l4)*64 + rslot);
#pragma unroll
    for (int m = 0; m < 4; ++m)
#pragma unroll
      for (int n = 0; n < 4; ++n)
        acc[m][n] = __builtin_amdgcn_mfma_f32_16x16x32_f16(af[m], bf[n], acc[m][n], 0, 0, 0);
  };

  stageA(0, 0); stageA(1, 1); stageB(0, 0);
  asm volatile("s_waitcnt vmcnt(0)" ::: "memory");
  BAR();
  int aCur = 0, aP2 = 2;
  for (int t = 0; t < nk; ++t) {
    if (t + 1 < nk) stageB(t + 1, (t + 1) & 1);
    if (t + 2 < nk) stageA(t + 2, aP2);
    compute(aCur, t & 1);
    if (t + 1 < nk) {
      if (t + 2 < nk) { asm volatile("s_waitcnt vmcnt(2)" ::: "memory"); }
      else            { asm volatile("s_waitcnt vmcnt(0)" ::: "memory"); }
      BAR();
    }
    aCur = (aCur == 2) ? 0 : aCur + 1;
    aP2  = (aP2  == 2) ? 0 : aP2  + 1;
  }

  const int cb = bn0 + wc*64, rb = bm0 + wr*64;
#pragma unroll
  for (int n = 0; n < 4; ++n) {
    const int col = cb + n*16 + l4;
    const float bvv = bias[col];
#pragma unroll
    for (int m = 0; m < 4; ++m)
#pragma unroll
      for (int j = 0; j < 4; ++j)
        C[(size_t)(rb + m*16 + lh*4 + j)*N + col] = (half_t)(acc[m][n][j] + bvv);
  }
}

// ---------------- builders (R11-verified) ----------------
// Bt1[b][r=h*80+s][k], 2048B rows, 3-bit swizzle (slot ^= r&7 within 128B K-groups)
__global__ __launch_bounds__(256, 2)
void w1_build(const half_t* __restrict__ kvb, const half_t* __restrict__ Wqc,
              half_t* __restrict__ Bt1) {
  __shared__ half_t K_lds[80*136];
  const int blk = blockIdx.x;
  const int b = blk >> 3, h = blk & 7;
  const int tid = threadIdx.x;
  const int l = tid & 63, w = tid >> 6;
  const int l4 = l & 15, lh = l >> 4;
  for (int i = tid; i < 80*16; i += 256) {
    int s = i >> 4, d = (i & 15) << 3;
    *(half8*)(K_lds + s*136 + d) =
        *(const half8*)(kvb + (size_t)(b*SKV_PAD + s)*2048 + h*128 + d);
  }
  __syncthreads();
  for (int c = 0; c < 4; ++c) {
    f32x4 acc[5][4] = {};
#pragma unroll
    for (int kt = 0; kt < 4; ++kt) {
      half8 af[5], bf[4];
#pragma unroll
      for (int m = 0; m < 5; ++m)
        af[m] = *(const half8*)(K_lds + (size_t)(m*16 + l4)*136 + kt*32 + lh*8);
#pragma unroll
      for (int n = 0; n < 4; ++n)
        bf[n] = *(const half8*)(Wqc + (size_t)(w*256 + c*64 + n*16 + l4)*1024 + h*128 + kt*32 + lh*8);
#pragma unroll
      for (int m = 0; m < 5; ++m)
#pragma unroll
        for (int n = 0; n < 4; ++n)
          acc[m][n] = __builtin_amdgcn_mfma_f32_16x16x32_f16(af[m], bf[n], acc[m][n], 0, 0, 0);
    }
#pragma unroll
    for (int n = 0; n < 4; ++n) {
      const int colk = w*256 + c*64 + n*16 + l4;
#pragma unroll
      for (int m = 0; m < 5; ++m)
#pragma unroll
        for (int j = 0; j < 4; ++j) {
          const int r = h*SKV_PAD + m*16 + lh*4 + j;
          size_t byte = ((size_t)(b*NKV_PAD + r))*2048 + (size_t)(colk >> 6)*128
                        + ((size_t)(((colk >> 3) & 7) ^ (r & 7)) << 4) + ((colk & 7) << 1);
          *(half_t*)((char*)Bt1 + byte) = (half_t)(acc[m][n][j]*ATTN_SCALE);
        }
    }
  }
}

// Bt2[b][n][c=h*80+s], 1280B rows, 3-bit swizzle (R10-verified)
__global__ __launch_bounds__(256, 2)
void w2_build(const half_t* __restrict__ kvb, const half_t* __restrict__ Wot,
              half_t* __restrict__ Bt2) {
  __shared__ half_t V_lds[80*136];
  const int blk = blockIdx.x;
  const int b = blk >> 3, h = blk & 7;
  const int tid = threadIdx.x;
  const int l = tid & 63, w = tid >> 6;
  const int l4 = l & 15, lh = l >> 4;
  for (int i = tid; i < 80*16; i += 256) {
    int s = i >> 4, d = (i & 15) << 3;
    *(half8*)(V_lds + s*136 + d) =
        *(const half8*)(kvb + (size_t)(b*SKV_PAD + s)*2048 + 1024 + h*128 + d);
  }
  __syncthreads();
  for (int c = 0; c < 4; ++c) {
    f32x4 acc[4][5] = {};
#pragma unroll
    for (int kt = 0; kt < 4; ++kt) {
      half8 af[4], bf[5];
#pragma unroll
      for (int m = 0; m < 4; ++m)
        af[m] = *(const half8*)(Wot + (size_t)(w*256 + c*64 + m*16 + l4)*1024 + h*128 + kt*32 + lh*8);
#pragma unroll
      for (int n = 0; n < 5; ++n)
        bf[n] = *(const half8*)(V_lds + (size_t)(n*16 + l4)*136 + kt*32 + lh*8);
#pragma unroll
      for (int m = 0; m < 4; ++m)
#pragma unroll
        for (int n = 0; n < 5; ++n)
          acc[m][n] = __builtin_amdgcn_mfma_f32_16x16x32_f16(af[m], bf[n], acc[m][n], 0, 0, 0);
    }
#pragma unroll
    for (int m = 0; m < 4; ++m) {
#pragma unroll
      for (int j = 0; j < 4; ++j) {
        const int nrow = w*256 + c*64 + m*16 + lh*4 + j;
        const size_t rowbase = ((size_t)(b*1024 + nrow))*1280;
#pragma unroll
        for (int n = 0; n < 5; ++n) {
          const int cc = h*80 + n*16 + l4;
          size_t byte = rowbase + (size_t)(cc >> 6)*128
                        + ((size_t)(((cc >> 3) & 7) ^ (nrow & 7)) << 4) + ((cc & 7) << 1);
          *(half_t*)((char*)Bt2 + byte) = (half_t)acc[m][n][j];
        }
      }
    }
  }
}

__global__ void c1_build(const half_t* __restrict__ kvb, const float* __restrict__ bq,
                         float* __restrict__ c1) {
  int idx = blockIdx.x * 256 + threadIdx.x;
  int b = idx / NKV, n = idx - b*NKV;
  int h = n / SKV_PAD, s = n - h*SKV_PAD;
  const half_t* kp = kvb + (size_t)(b*SKV_PAD + s)*2048 + h*128;
  float acc = 0.f;
#pragma unroll 8
  for (int d = 0; d < 128; ++d) acc += bq[h*128 + d] * (float)kp[d];
  c1[idx] = acc * ATTN_SCALE;
}

// ---------------- FUSED: S = x@W1 -> softmax (LDS) -> out = P@W2 ----------------
// One block per 64-row tile. 512 thr / 8 waves. S never touches HBM.
// S_lds: [64 rows][640] fp16, 1280B rows, 3-bit swizzle (= verified global-S layout).
// x staged per BK=64 chunk (fp32->fp16 reg-split, R7's T14 pattern), 3-bit-swizzled 128B rows.
// W1/W2 B-frags read directly from L2 (per-XCD batch residency; no cross-wave redundancy).
__global__ __launch_bounds__(512, 2)
void fused_sv(const float* __restrict__ X, const half_t* __restrict__ Bt1,
              const float* __restrict__ c1, const half_t* __restrict__ Bt2,
              const float* __restrict__ bo, float* __restrict__ out) {
  __shared__ half_t S_lds[64*640];       // 80 KB
  __shared__ half_t x_lds[2][64*64];     // 2 x 8 KB
  const int tid = threadIdx.x;
  const int l = tid & 63, w = tid >> 6;
  const int l4 = l & 15, lh = l >> 4;
  const int k7 = l4 & 7;                 // per-lane swizzle key (row&7 == l4&7 on all frag paths)

  // XCD-chunked: blocks with equal blk&7 share an XCD; each XCD owns one batch.
  const int lin = ((int)blockIdx.x & 7)*64 + ((int)blockIdx.x >> 3);
  const int batch = lin >> 6;
  const int row0 = batch*SEQ_Q + (lin & 63)*64;
  const half_t* W1 = Bt1 + (size_t)batch*NKV_PAD*1024;   // 2048B rows (rows 0..639 used)
  const half_t* W2 = Bt2 + (size_t)batch*1024*NKV;       // 1280B rows
  const float* c1b = c1 + batch*NKV;

  // ================= S phase: S[64x640] = x[64x1024] @ W1^T =================
  // wave w owns n-frags [w*5, w*5+5) (cols w*80..w*80+80), all 4 m-frags.
  f32x4 sacc[4][5] = {};
  const int nfb = w*5;

  // x reg-staging: thread -> row tid>>3, 8 floats at col (tid&7)*8
  const int xrow = tid >> 3, xc8 = tid & 7;
  const float* xg = X + (size_t)(row0 + xrow)*1024 + xc8*8;
  f32x4 xa, xb;
  auto xload = [&](int kc) {
    const float* g = xg + kc*64;
    xa = *(const f32x4*)g; xb = *(const f32x4*)(g + 4);
  };
  auto xwrite = [&](int buf) {
    half8 h;
#pragma unroll
    for (int e = 0; e < 4; ++e) { h[e] = (half_t)xa[e]; h[e+4] = (half_t)xb[e]; }
    *(half8*)((char*)x_lds[buf] + xrow*128 + ((xc8 ^ (xrow & 7)) << 4)) = h;
  };

  xload(0); xwrite(0);
  __syncthreads();

  for (int kc = 0; kc < 16; ++kc) {
    if (kc + 1 < 16) xload(kc + 1);                    // issue early (T14)
    const char* xc = (const char*)x_lds[kc & 1];
#pragma unroll
    for (int kk = 0; kk < 2; ++kk) {
      half8 af[4];
#pragma unroll
      for (int m = 0; m < 4; ++m)
        af[m] = *(const half8*)(xc + (size_t)(m*16 + l4)*128 + (((kk*4 + lh) ^ k7) << 4));
#pragma unroll
      for (int nf = 0; nf < 5; ++nf) {
        const int nrow = (nfb + nf)*16 + l4;
        half8 bfv = *(const half8*)((const char*)W1 + (size_t)nrow*2048 + (size_t)kc*128
                                    + (((kk*4 + lh) ^ k7) << 4));
#pragma unroll
        for (int m = 0; m < 4; ++m)
          sacc[m][nf] = __builtin_amdgcn_mfma_f32_16x16x32_f16(af[m], bfv, sacc[m][nf], 0, 0, 0);
      }
    }
    if (kc + 1 < 16) {
      xwrite((kc + 1) & 1);                            // cvt + ds_write late
      __syncthreads();
    }
  }

  // dump S-frags to S_lds (3-bit swizzle; same math as verified gemm8p_s epilogue)
#pragma unroll
  for (int nf = 0; nf < 5; ++nf) {
    const int col = (nfb + nf)*16 + l4;
#pragma unroll
    for (int m = 0; m < 4; ++m)
#pragma unroll
      for (int j = 0; j < 4; ++j) {
        const int row = m*16 + lh*4 + j;
        size_t byte = (size_t)row*1280 + (size_t)(col >> 6)*128
                      + ((size_t)(((col >> 3) & 7) ^ (row & 7)) << 4) + ((col & 7) << 1);
        *(half_t*)((char*)S_lds + byte) = (half_t)sacc[m][nf][j];
      }
  }
  __syncthreads();

  // ================= softmax in LDS (thread = one (row, head)) =================
  {
    const int row = tid >> 3, h = tid & 7;
    const int key = row & 7;
    char* base = (char*)S_lds + (size_t)row*1280;
    float fv[10][8];
    float mx = -1e30f;
#pragma unroll
    for (int i = 0; i < 10; ++i) {
      const int ls = h*10 + i;
      half8 v = *(const half8*)(base + (size_t)(ls >> 3)*128 + ((size_t)((ls & 7) ^ key) << 4));
      f32x4 ca = *(const f32x4*)(c1b + h*80 + i*8);
      f32x4 cb = *(const f32x4*)(c1b + h*80 + i*8 + 4);
#pragma unroll
      for (int j = 0; j < 8; ++j) {
        const float cc = (j < 4) ? ca[j] : cb[j - 4];
        const float sv = (float)v[j] + cc;
        const bool ok = (i*8 + j) < SEQ_KV;
        fv[i][j] = ok ? sv : -1e30f;
        if (ok) mx = fmaxf(mx, sv);
      }
    }
    float sm = 0.f;
#pragma unroll
    for (int i = 0; i < 10; ++i)
#pragma unroll
      for (int j = 0; j < 8; ++j) { float e = __expf(fv[i][j] - mx); sm += e; fv[i][j] = e; }
    const float inv = 1.f / sm;
#pragma unroll
    for (int i = 0; i < 10; ++i) {
      const int ls = h*10 + i;
      half8 t;
#pragma unroll
      for (int j = 0; j < 8; ++j) t[j] = (half_t)(fv[i][j] * inv);
      *(half8*)(base + (size_t)(ls >> 3)*128 + ((size_t)((ls & 7) ^ key) << 4)) = t;
    }
  }
  __syncthreads();

  // ================= P phase: out[64x1024] = P[64x640] @ W2^T =================
  // wave w owns out cols [w*128, w*128+128): 4 m-frags x 8 n-frags.
  f32x4 oacc[4][8] = {};
  const int ncb = w*128;
  for (int ks = 0; ks < 20; ++ks) {
    const size_t koff = (size_t)(ks >> 1)*128 + ((((ks & 1)*4 + lh) ^ k7) << 4);
    half8 af[4];
#pragma unroll
    for (int m = 0; m < 4; ++m)
      af[m] = *(const half8*)((const char*)S_lds + (size_t)(m*16 + l4)*1280 + koff);
#pragma unroll
    for (int nf = 0; nf < 8; ++nf) {
      const int nrow = ncb + nf*16 + l4;
      half8 bfv = *(const half8*)((const char*)W2 + (size_t)nrow*1280 + koff);
#pragma unroll
      for (int m = 0; m < 4; ++m)
        oacc[m][nf] = __builtin_amdgcn_mfma_f32_16x16x32_f16(af[m], bfv, oacc[m][nf], 0, 0, 0);
    }
  }

  // epilogue: out fp32 + bo
#pragma unroll
  for (int nf = 0; nf < 8; ++nf) {
    const int col = ncb + nf*16 + l4;
    const float bvv = bo[col];
#pragma unroll
    for (int m = 0; m < 4; ++m)
#pragma unroll
      for (int j = 0; j < 4; ++j) {
        const int row = row0 + m*16 + lh*4 + j;
        out[(size_t)row*1024 + col] = oacc[m][nf][j] + bvv;
      }
  }
}

// ---------------- launch ----------------
extern "C" void kernel_launch(void* const* d_in, const int* in_sizes, int n_in,
                              void* d_out, int out_size, void* d_ws, size_t ws_size,
                              hipStream_t stream) {
  (void)in_sizes; (void)n_in; (void)out_size; (void)ws_size;
  const float* x  = (const float*)d_in[0];
  const float* y  = (const float*)d_in[1];
  const float* Wq = (const float*)d_in[2];
  const float* bq = (const float*)d_in[3];
  const float* Wk = (const float*)d_in[4];
  const float* bk = (const float*)d_in[5];
  const float* Wv = (const float*)d_in[6];
  const float* bv = (const float*)d_in[7];
  const float* Wo = (const float*)d_in[8];
  const float* bo = (const float*)d_in[9];

  char* ws = (char*)d_ws;
  half_t* Wqc  = (half_t*)(ws + WS_WQC);
  half_t* Wot  = (half_t*)(ws + WS_WOT);
  half_t* Wkvt = (half_t*)(ws + WS_WKVT);
  half_t* yh   = (half_t*)(ws + WS_YH);
  half_t* kvb  = (half_t*)(ws + WS_KV);
  float*  bkv  = (float*)(ws + WS_BKV);
  half_t* Bt1  = (half_t*)(ws + WS_BT1);
  half_t* Bt2  = (half_t*)(ws + WS_BT2);
  float*  c1   = (float*)(ws + WS_C1);

  dim3 tb(32, 8);
  cast_f32_f16<<<512, 256, 0, stream>>>(Wq, Wqc);
  transpose_f32f16<<<dim3(32, 32), tb, 0, stream>>>(Wo, Wot, 1024, 1024);
  transpose_f32f16<<<dim3(32, 24), tb, 0, stream>>>(Wk, Wkvt, 768, 1024);
  transpose_f32f16<<<dim3(32, 24), tb, 0, stream>>>(Wv, Wkvt + (size_t)1024*768, 768, 1024);
  convert_pad_y<<<BATCH*SKV_PAD*D_CROSS/256, 256, 0, stream>>>(y, yh);
  concat_bias<<<2*D_EMBED/256, 256, 0, stream>>>(bk, bv, bkv);

  // K/V projection
  gemm_kv<<<dim3(16, 5), 256, 0, stream>>>(yh, Wkvt, bkv, kvb, BATCH*SKV_PAD, 2048, 768);

  // folded-weight builders
  c1_build<<<BATCH*NKV/256, 256, 0, stream>>>(kvb, bq, c1);
  w1_build<<<BATCH*N_HEADS, 256, 0, stream>>>(kvb, Wqc, Bt1);
  w2_build<<<BATCH*N_HEADS, 256, 0, stream>>>(kvb, Wot, Bt2);

  // fused S-GEMM + softmax + out-GEMM (S stays in LDS)
  fused_sv<<<512, 512, 0, stream>>>(x, Bt1, c1, Bt2, bo, (float*)d_out);
}

// Round 14
// 248.109 us; speedup vs baseline: 1.3640x; 1.0437x over previous
//
#include <hip/hip_runtime.h>

typedef _Float16 half_t;
typedef _Float16 half8 __attribute__((ext_vector_type(8)));
typedef float f32x4 __attribute__((ext_vector_type(4)));

#define D_EMBED   1024
#define D_CROSS   768
#define N_HEADS   8
#define D_HEAD    128
#define BATCH     8
#define SEQ_Q     4096
#define SEQ_KV    77
#define SKV_PAD   80
#define NKV       (N_HEADS*SKV_PAD)     /* 640 */
#define NKV_PAD   768                   /* Bt1 row-dim padding (rows 640..767 never read) */
#define M_Q       (BATCH*SEQ_Q)         /* 32768 */

// ---------------- workspace layout (bytes) ----------------
#define WS_S     ((size_t)0)                                   // (unused)
#define WS_WQC   (WS_S    + (size_t)M_Q*NKV*2)
#define WS_WOT   (WS_WQC  + (size_t)D_EMBED*D_EMBED*2)
#define WS_WKVT  (WS_WOT  + (size_t)D_EMBED*D_EMBED*2)
#define WS_YH    (WS_WKVT + (size_t)2*D_EMBED*D_CROSS*2)
#define WS_KV    (WS_YH   + (size_t)BATCH*SKV_PAD*D_CROSS*2)
#define WS_BKV   (WS_KV   + (size_t)BATCH*SKV_PAD*2*D_EMBED*2)
#define WS_BT1   (WS_BKV  + (size_t)2*D_EMBED*4)               // W1^T fp16 [8][768][1024] 3-bit swz, 2048B rows
#define WS_BT2   (WS_BT1  + (size_t)BATCH*NKV_PAD*D_EMBED*2)   // W2^T fp16 [8][1024][640] 3-bit swz, 1280B rows
#define WS_C1    (WS_BT2  + (size_t)BATCH*D_EMBED*NKV*2)       // c1 fp32 [8][640]

#define ATTN_SCALE 0.08838834764831845f

__device__ __forceinline__ void gload_lds16(const void* g, void* lds) {
  __builtin_amdgcn_global_load_lds(
      (const __attribute__((address_space(1))) unsigned int*)g,
      (__attribute__((address_space(3))) unsigned int*)lds, 16, 0, 0);
}
__device__ __forceinline__ void BAR() {
  __builtin_amdgcn_s_barrier();
  __builtin_amdgcn_sched_barrier(0);
}

// ---------------- prep kernels ----------------
__global__ void cast_f32_f16(const float* __restrict__ src, half_t* __restrict__ dst) {
  int i = blockIdx.x * 256 + threadIdx.x;
  f32x4 a = *(const f32x4*)(src + (size_t)i*8);
  f32x4 b = *(const f32x4*)(src + (size_t)i*8 + 4);
  half8 h;
#pragma unroll
  for (int j = 0; j < 4; ++j) { h[j] = (half_t)a[j]; h[j+4] = (half_t)b[j]; }
  *(half8*)(dst + (size_t)i*8) = h;
}

__global__ void transpose_f32f16(const float* __restrict__ src, half_t* __restrict__ dst,
                                 int K, int N) {
  __shared__ float tile[32][33];
  int n0 = blockIdx.x * 32, k0 = blockIdx.y * 32;
  int tx = threadIdx.x, ty = threadIdx.y;
#pragma unroll
  for (int j = 0; j < 4; ++j)
    tile[ty + j*8][tx] = src[(size_t)(k0 + ty + j*8)*N + n0 + tx];
  __syncthreads();
#pragma unroll
  for (int j = 0; j < 4; ++j)
    dst[(size_t)(n0 + ty + j*8)*K + k0 + tx] = (half_t)tile[tx][ty + j*8];
}

__global__ void convert_pad_y(const float* __restrict__ y, half_t* __restrict__ yh) {
  int idx = blockIdx.x * 256 + threadIdx.x;
  int r = idx / D_CROSS, col = idx - r*D_CROSS;
  int b = r / SKV_PAD, s = r - b*SKV_PAD;
  yh[idx] = (s < SEQ_KV) ? (half_t)y[(size_t)(b*SEQ_KV + s)*D_CROSS + col] : (half_t)0.f;
}

__global__ void concat_bias(const float* __restrict__ bk, const float* __restrict__ bv,
                            float* __restrict__ bkv) {
  int i = blockIdx.x * 256 + threadIdx.x;
  bkv[i] = (i < D_EMBED) ? bk[i] : bv[i - D_EMBED];
}

// ---------------- 128x128 GEMM — K/V projection (R7-verified) ----------------
__global__ __launch_bounds__(256, 3)
void gemm_kv(const half_t* __restrict__ A, const half_t* __restrict__ Bt,
             const float* __restrict__ bias, half_t* __restrict__ C,
             int M, int N, int K) {
  __shared__ half_t As[3][128*32];
  __shared__ half_t Bs[2][128*32];
  const int tid = threadIdx.x;
  const int l = tid & 63, w = tid >> 6;
  const int l4 = l & 15, lh = l >> 4;
  const int bn0 = blockIdx.x * 128, bm0 = blockIdx.y * 128;
  const int wr = w >> 1, wc = w & 1;
  const int rslot = lh << 4;
  f32x4 acc[4][4] = {};
  const int nk = K >> 5;
  const int srow = w*16 + (l >> 2);
  const int scol = (l & 3)*8;

  auto stageB = [&](int kt, int bb) {
    const half_t* g = Bt + (size_t)(bn0 + srow)*K + scol + kt*32;
    gload_lds16(g,                 (char*)Bs[bb] + w*1024);
    gload_lds16(g + (size_t)64*K,  (char*)Bs[bb] + 4096 + w*1024);
  };
  auto stageA = [&](int kt, int bb) {
    const half_t* g = A + (size_t)(bm0 + srow)*K + scol + kt*32;
    gload_lds16(g,                 (char*)As[bb] + w*1024);
    gload_lds16(g + (size_t)64*K,  (char*)As[bb] + 4096 + w*1024);
  };
  auto compute = [&](int ab, int bb) {
    half8 af[4], bf[4];
#pragma unroll
    for (int m = 0; m < 4; ++m)
      af[m] = *(const half8*)((const char*)As[ab] + (size_t)(wr*64 + m*16 + l4)*64 + rslot);
#pragma unroll
    for (int n = 0; n < 4; ++n)
      bf[n] = *(const half8*)((const char*)Bs[bb] + (size_t)(wc*64 + n*16 + l4)*64 + rslot);
#pragma unroll
    for (int m = 0; m < 4; ++m)
#pragma unroll
      for (int n = 0; n < 4; ++n)
        acc[m][n] = __builtin_amdgcn_mfma_f32_16x16x32_f16(af[m], bf[n], acc[m][n], 0, 0, 0);
  };

  stageA(0, 0); stageA(1, 1); stageB(0, 0);
  asm volatile("s_waitcnt vmcnt(0)" ::: "memory");
  BAR();
  int aCur = 0, aP2 = 2;
  for (int t = 0; t < nk; ++t) {
    if (t + 1 < nk) stageB(t + 1, (t + 1) & 1);
    if (t + 2 < nk) stageA(t + 2, aP2);
    compute(aCur, t & 1);
    if (t + 1 < nk) {
      if (t + 2 < nk) { asm volatile("s_waitcnt vmcnt(2)" ::: "memory"); }
      else            { asm volatile("s_waitcnt vmcnt(0)" ::: "memory"); }
      BAR();
    }
    aCur = (aCur == 2) ? 0 : aCur + 1;
    aP2  = (aP2  == 2) ? 0 : aP2  + 1;
  }

  const int cb = bn0 + wc*64, rb = bm0 + wr*64;
#pragma unroll
  for (int n = 0; n < 4; ++n) {
    const int col = cb + n*16 + l4;
    const float bvv = bias[col];
#pragma unroll
    for (int m = 0; m < 4; ++m)
#pragma unroll
      for (int j = 0; j < 4; ++j)
        C[(size_t)(rb + m*16 + lh*4 + j)*N + col] = (half_t)(acc[m][n][j] + bvv);
  }
}

// ---------------- builders (R11/R13-verified) ----------------
__global__ __launch_bounds__(256, 2)
void w1_build(const half_t* __restrict__ kvb, const half_t* __restrict__ Wqc,
              half_t* __restrict__ Bt1) {
  __shared__ half_t K_lds[80*136];
  const int blk = blockIdx.x;
  const int b = blk >> 3, h = blk & 7;
  const int tid = threadIdx.x;
  const int l = tid & 63, w = tid >> 6;
  const int l4 = l & 15, lh = l >> 4;
  for (int i = tid; i < 80*16; i += 256) {
    int s = i >> 4, d = (i & 15) << 3;
    *(half8*)(K_lds + s*136 + d) =
        *(const half8*)(kvb + (size_t)(b*SKV_PAD + s)*2048 + h*128 + d);
  }
  __syncthreads();
  for (int c = 0; c < 4; ++c) {
    f32x4 acc[5][4] = {};
#pragma unroll
    for (int kt = 0; kt < 4; ++kt) {
      half8 af[5], bf[4];
#pragma unroll
      for (int m = 0; m < 5; ++m)
        af[m] = *(const half8*)(K_lds + (size_t)(m*16 + l4)*136 + kt*32 + lh*8);
#pragma unroll
      for (int n = 0; n < 4; ++n)
        bf[n] = *(const half8*)(Wqc + (size_t)(w*256 + c*64 + n*16 + l4)*1024 + h*128 + kt*32 + lh*8);
#pragma unroll
      for (int m = 0; m < 5; ++m)
#pragma unroll
        for (int n = 0; n < 4; ++n)
          acc[m][n] = __builtin_amdgcn_mfma_f32_16x16x32_f16(af[m], bf[n], acc[m][n], 0, 0, 0);
    }
#pragma unroll
    for (int n = 0; n < 4; ++n) {
      const int colk = w*256 + c*64 + n*16 + l4;
#pragma unroll
      for (int m = 0; m < 5; ++m)
#pragma unroll
        for (int j = 0; j < 4; ++j) {
          const int r = h*SKV_PAD + m*16 + lh*4 + j;
          size_t byte = ((size_t)(b*NKV_PAD + r))*2048 + (size_t)(colk >> 6)*128
                        + ((size_t)(((colk >> 3) & 7) ^ (r & 7)) << 4) + ((colk & 7) << 1);
          *(half_t*)((char*)Bt1 + byte) = (half_t)(acc[m][n][j]*ATTN_SCALE);
        }
    }
  }
}

__global__ __launch_bounds__(256, 2)
void w2_build(const half_t* __restrict__ kvb, const half_t* __restrict__ Wot,
              half_t* __restrict__ Bt2) {
  __shared__ half_t V_lds[80*136];
  const int blk = blockIdx.x;
  const int b = blk >> 3, h = blk & 7;
  const int tid = threadIdx.x;
  const int l = tid & 63, w = tid >> 6;
  const int l4 = l & 15, lh = l >> 4;
  for (int i = tid; i < 80*16; i += 256) {
    int s = i >> 4, d = (i & 15) << 3;
    *(half8*)(V_lds + s*136 + d) =
        *(const half8*)(kvb + (size_t)(b*SKV_PAD + s)*2048 + 1024 + h*128 + d);
  }
  __syncthreads();
  for (int c = 0; c < 4; ++c) {
    f32x4 acc[4][5] = {};
#pragma unroll
    for (int kt = 0; kt < 4; ++kt) {
      half8 af[4], bf[5];
#pragma unroll
      for (int m = 0; m < 4; ++m)
        af[m] = *(const half8*)(Wot + (size_t)(w*256 + c*64 + m*16 + l4)*1024 + h*128 + kt*32 + lh*8);
#pragma unroll
      for (int n = 0; n < 5; ++n)
        bf[n] = *(const half8*)(V_lds + (size_t)(n*16 + l4)*136 + kt*32 + lh*8);
#pragma unroll
      for (int m = 0; m < 4; ++m)
#pragma unroll
        for (int n = 0; n < 5; ++n)
          acc[m][n] = __builtin_amdgcn_mfma_f32_16x16x32_f16(af[m], bf[n], acc[m][n], 0, 0, 0);
    }
#pragma unroll
    for (int m = 0; m < 4; ++m) {
#pragma unroll
      for (int j = 0; j < 4; ++j) {
        const int nrow = w*256 + c*64 + m*16 + lh*4 + j;
        const size_t rowbase = ((size_t)(b*1024 + nrow))*1280;
#pragma unroll
        for (int n = 0; n < 5; ++n) {
          const int cc = h*80 + n*16 + l4;
          size_t byte = rowbase + (size_t)(cc >> 6)*128
                        + ((size_t)(((cc >> 3) & 7) ^ (nrow & 7)) << 4) + ((cc & 7) << 1);
          *(half_t*)((char*)Bt2 + byte) = (half_t)acc[m][n][j];
        }
      }
    }
  }
}

__global__ void c1_build(const half_t* __restrict__ kvb, const float* __restrict__ bq,
                         float* __restrict__ c1) {
  int idx = blockIdx.x * 256 + threadIdx.x;
  int b = idx / NKV, n = idx - b*NKV;
  int h = n / SKV_PAD, s = n - h*SKV_PAD;
  const half_t* kp = kvb + (size_t)(b*SKV_PAD + s)*2048 + h*128;
  float acc = 0.f;
#pragma unroll 8
  for (int d = 0; d < 128; ++d) acc += bq[h*128 + d] * (float)kp[d];
  c1[idx] = acc * ATTN_SCALE;
}

// ---------------- FUSED v2: register-prefetched B, raw barriers ----------------
// One block per 64-row tile, 512 thr / 8 waves, 1 block/CU (96 KB LDS).
// S phase: per step (kc,kk), B-frags (5x16B from L2) prefetched ONE STEP AHEAD into
// ping-pong regs b0/b1 -> MFMA never waits on L2 inline. x staged via T14 reg-split
// into dbuf x_lds; raw lgkm(0)+s_barrier per kc (register prefetches survive barriers).
// P phase: 2 passes of 4 n-frags (acc 64 regs), same depth-1 prefetch, no barriers.
__global__ __launch_bounds__(512, 1)
void fused_sv(const float* __restrict__ X, const half_t* __restrict__ Bt1,
              const float* __restrict__ c1, const half_t* __restrict__ Bt2,
              const float* __restrict__ bo, float* __restrict__ out) {
  __shared__ half_t S_lds[64*640];       // 80 KB
  __shared__ half_t x_lds[2][64*64];     // 2 x 8 KB
  const int tid = threadIdx.x;
  const int l = tid & 63, w = tid >> 6;
  const int l4 = l & 15, lh = l >> 4;
  const int k7 = l4 & 7;

  const int lin = ((int)blockIdx.x & 7)*64 + ((int)blockIdx.x >> 3);
  const int batch = lin >> 6;
  const int row0 = batch*SEQ_Q + (lin & 63)*64;
  const char* W1 = (const char*)(Bt1 + (size_t)batch*NKV_PAD*1024);
  const char* W2 = (const char*)(Bt2 + (size_t)batch*1024*NKV);
  const float* c1b = c1 + batch*NKV;

  // ================= S phase =================
  f32x4 sacc[4][5] = {};
  const int nfb = w*5;

  const int xrow = tid >> 3, xc8 = tid & 7;
  const float* xg = X + (size_t)(row0 + xrow)*1024 + xc8*8;
  f32x4 xa, xb;
  auto xload = [&](int kc) {
    const float* g = xg + kc*64;
    xa = *(const f32x4*)g; xb = *(const f32x4*)(g + 4);
  };
  auto xwrite = [&](int buf) {
    half8 h;
#pragma unroll
    for (int e = 0; e < 4; ++e) { h[e] = (half_t)xa[e]; h[e+4] = (half_t)xb[e]; }
    *(half8*)((char*)x_lds[buf] + xrow*128 + ((xc8 ^ (xrow & 7)) << 4)) = h;
  };

  half8 b0[5], b1[5];
  auto bload = [&](int t, half8* dst) {
    const int kc = t >> 1, kk = t & 1;
    const size_t koff = (size_t)kc*128 + (size_t)(((kk*4 + lh) ^ k7) << 4);
#pragma unroll
    for (int nf = 0; nf < 5; ++nf)
      dst[nf] = *(const half8*)(W1 + (size_t)((nfb + nf)*16 + l4)*2048 + koff);
  };
  auto smfma = [&](const half8* bf, int kc, int kk) {
    const char* xc = (const char*)x_lds[kc & 1];
    half8 af[4];
#pragma unroll
    for (int m = 0; m < 4; ++m)
      af[m] = *(const half8*)(xc + (size_t)(m*16 + l4)*128 + (((kk*4 + lh) ^ k7) << 4));
    __builtin_amdgcn_s_setprio(1);
#pragma unroll
    for (int nf = 0; nf < 5; ++nf)
#pragma unroll
      for (int m = 0; m < 4; ++m)
        sacc[m][nf] = __builtin_amdgcn_mfma_f32_16x16x32_f16(af[m], bf[nf], sacc[m][nf], 0, 0, 0);
    __builtin_amdgcn_s_setprio(0);
  };

  xload(0); xwrite(0);
  bload(0, b0);
  asm volatile("s_waitcnt lgkmcnt(0)" ::: "memory");
  BAR();

  for (int kc = 0; kc < 16; ++kc) {
    if (kc + 1 < 16) xload(kc + 1);            // issue early (T14)
    bload(2*kc + 1, b1);                        // prefetch next step's B
    smfma(b0, kc, 0);
    if (2*kc + 2 < 32) bload(2*kc + 2, b0);     // prefetch step after
    smfma(b1, kc, 1);
    if (kc + 1 < 16) {
      xwrite((kc + 1) & 1);                     // cvt + ds_write late
      asm volatile("s_waitcnt lgkmcnt(0)" ::: "memory");
      BAR();                                    // raw: B prefetches stay in flight
    }
  }

  // dump S-frags to S_lds (3-bit swizzle; verified R10/R13)
#pragma unroll
  for (int nf = 0; nf < 5; ++nf) {
    const int col = (nfb + nf)*16 + l4;
#pragma unroll
    for (int m = 0; m < 4; ++m)
#pragma unroll
      for (int j = 0; j < 4; ++j) {
        const int row = m*16 + lh*4 + j;
        size_t byte = (size_t)row*1280 + (size_t)(col >> 6)*128
                      + ((size_t)(((col >> 3) & 7) ^ (row & 7)) << 4) + ((col & 7) << 1);
        *(half_t*)((char*)S_lds + byte) = (half_t)sacc[m][nf][j];
      }
  }
  asm volatile("s_waitcnt lgkmcnt(0)" ::: "memory");
  BAR();

  // ================= softmax in LDS (verified R13) =================
  {
    const int row = tid >> 3, h = tid & 7;
    const int key = row & 7;
    char* base = (char*)S_lds + (size_t)row*1280;
    float fv[10][8];
    float mx = -1e30f;
#pragma unroll
    for (int i = 0; i < 10; ++i) {
      const int ls = h*10 + i;
      half8 v = *(const half8*)(base + (size_t)(ls >> 3)*128 + ((size_t)((ls & 7) ^ key) << 4));
      f32x4 ca = *(const f32x4*)(c1b + h*80 + i*8);
      f32x4 cb = *(const f32x4*)(c1b + h*80 + i*8 + 4);
#pragma unroll
      for (int j = 0; j < 8; ++j) {
        const float cc = (j < 4) ? ca[j] : cb[j - 4];
        const float sv = (float)v[j] + cc;
        const bool ok = (i*8 + j) < SEQ_KV;
        fv[i][j] = ok ? sv : -1e30f;
        if (ok) mx = fmaxf(mx, sv);
      }
    }
    float sm = 0.f;
#pragma unroll
    for (int i = 0; i < 10; ++i)
#pragma unroll
      for (int j = 0; j < 8; ++j) { float e = __expf(fv[i][j] - mx); sm += e; fv[i][j] = e; }
    const float inv = 1.f / sm;
#pragma unroll
    for (int i = 0; i < 10; ++i) {
      const int ls = h*10 + i;
      half8 t;
#pragma unroll
      for (int j = 0; j < 8; ++j) t[j] = (half_t)(fv[i][j] * inv);
      *(half8*)(base + (size_t)(ls >> 3)*128 + ((size_t)((ls & 7) ^ key) << 4)) = t;
    }
  }
  asm volatile("s_waitcnt lgkmcnt(0)" ::: "memory");
  BAR();

  // ================= P phase: 2 passes of 4 n-frags, depth-1 B prefetch =================
#pragma unroll 1
  for (int pass = 0; pass < 2; ++pass) {
    f32x4 oacc[4][4] = {};
    half8 p0[4], p1[4];
    const int ncb = w*128 + pass*64;
    auto pbload = [&](int ks, half8* dst) {
      const size_t koff = (size_t)(ks >> 1)*128 + (size_t)((((ks & 1)*4 + lh) ^ k7) << 4);
#pragma unroll
      for (int nf = 0; nf < 4; ++nf)
        dst[nf] = *(const half8*)(W2 + (size_t)(ncb + nf*16 + l4)*1280 + koff);
    };
    auto pmfma = [&](const half8* bf, int ks) {
      const size_t koff = (size_t)(ks >> 1)*128 + (size_t)((((ks & 1)*4 + lh) ^ k7) << 4);
      half8 af[4];
#pragma unroll
      for (int m = 0; m < 4; ++m)
        af[m] = *(const half8*)((const char*)S_lds + (size_t)(m*16 + l4)*1280 + koff);
      __builtin_amdgcn_s_setprio(1);
#pragma unroll
      for (int nf = 0; nf < 4; ++nf)
#pragma unroll
        for (int m = 0; m < 4; ++m)
          oacc[m][nf] = __builtin_amdgcn_mfma_f32_16x16x32_f16(af[m], bf[nf], oacc[m][nf], 0, 0, 0);
      __builtin_amdgcn_s_setprio(0);
    };

    pbload(0, p0);
    for (int ks = 0; ks < 20; ks += 2) {
      pbload(ks + 1, p1);
      pmfma(p0, ks);
      if (ks + 2 < 20) pbload(ks + 2, p0);
      pmfma(p1, ks + 1);
    }

    // epilogue for this pass
#pragma unroll
    for (int nf = 0; nf < 4; ++nf) {
      const int col = ncb + nf*16 + l4;
      const float bvv = bo[col];
#pragma unroll
      for (int m = 0; m < 4; ++m)
#pragma unroll
        for (int j = 0; j < 4; ++j) {
          const int row = row0 + m*16 + lh*4 + j;
          out[(size_t)row*1024 + col] = oacc[m][nf][j] + bvv;
        }
    }
  }
}

// ---------------- launch ----------------
extern "C" void kernel_launch(void* const* d_in, const int* in_sizes, int n_in,
                              void* d_out, int out_size, void* d_ws, size_t ws_size,
                              hipStream_t stream) {
  (void)in_sizes; (void)n_in; (void)out_size; (void)ws_size;
  const float* x  = (const float*)d_in[0];
  const float* y  = (const float*)d_in[1];
  const float* Wq = (const float*)d_in[2];
  const float* bq = (const float*)d_in[3];
  const float* Wk = (const float*)d_in[4];
  const float* bk = (const float*)d_in[5];
  const float* Wv = (const float*)d_in[6];
  const float* bv = (const float*)d_in[7];
  const float* Wo = (const float*)d_in[8];
  const float* bo = (const float*)d_in[9];

  char* ws = (char*)d_ws;
  half_t* Wqc  = (half_t*)(ws + WS_WQC);
  half_t* Wot  = (half_t*)(ws + WS_WOT);
  half_t* Wkvt = (half_t*)(ws + WS_WKVT);
  half_t* yh   = (half_t*)(ws + WS_YH);
  half_t* kvb  = (half_t*)(ws + WS_KV);
  float*  bkv  = (float*)(ws + WS_BKV);
  half_t* Bt1  = (half_t*)(ws + WS_BT1);
  half_t* Bt2  = (half_t*)(ws + WS_BT2);
  float*  c1   = (float*)(ws + WS_C1);

  dim3 tb(32, 8);
  cast_f32_f16<<<512, 256, 0, stream>>>(Wq, Wqc);
  transpose_f32f16<<<dim3(32, 32), tb, 0, stream>>>(Wo, Wot, 1024, 1024);
  transpose_f32f16<<<dim3(32, 24), tb, 0, stream>>>(Wk, Wkvt, 768, 1024);
  transpose_f32f16<<<dim3(32, 24), tb, 0, stream>>>(Wv, Wkvt + (size_t)1024*768, 768, 1024);
  convert_pad_y<<<BATCH*SKV_PAD*D_CROSS/256, 256, 0, stream>>>(y, yh);
  concat_bias<<<2*D_EMBED/256, 256, 0, stream>>>(bk, bv, bkv);

  // K/V projection
  gemm_kv<<<dim3(16, 5), 256, 0, stream>>>(yh, Wkvt, bkv, kvb, BATCH*SKV_PAD, 2048, 768);

  // folded-weight builders
  c1_build<<<BATCH*NKV/256, 256, 0, stream>>>(kvb, bq, c1);
  w1_build<<<BATCH*N_HEADS, 256, 0, stream>>>(kvb, Wqc, Bt1);
  w2_build<<<BATCH*N_HEADS, 256, 0, stream>>>(kvb, Wot, Bt2);

  // fused S-GEMM + softmax + out-GEMM (S stays in LDS)
  fused_sv<<<512, 512, 0, stream>>>(x, Bt1, c1, Bt2, bo, (float*)d_out);
}